// Round 9
// baseline (319.471 us; speedup 1.0000x reference)
//
#include <hip/hip_runtime.h>

#define DEVI static __device__ __forceinline__

using s16x8 = __attribute__((ext_vector_type(8))) short;
using f32x4 = __attribute__((ext_vector_type(4))) float;
using u32x4 = __attribute__((ext_vector_type(4))) unsigned int;

static constexpr int H  = 16;
static constexpr int S  = 1024;
static constexpr int DM = 1024;
static constexpr int NB = 2;          // batch
static constexpr int BS = NB * S;     // 2048
static constexpr long SS  = (long)S * S;
static constexpr long HSS = (long)H * SS;
static constexpr long SDM = (long)S * DM;

DEVI unsigned short f2bf(float f) {
    union { float f; unsigned u; } c; c.f = f;
    c.u += 0x7FFFu + ((c.u >> 16) & 1u);   // RNE
    return (unsigned short)(c.u >> 16);
}
DEVI float bf2f(unsigned short v) {
    union { unsigned u; float f; } c; c.u = ((unsigned)v) << 16;
    return c.f;
}

// async global->LDS, 16 bytes per lane; lds dest = wave-uniform base + lane*16
DEVI void gload16(const unsigned short* g, unsigned short* l) {
    __builtin_amdgcn_global_load_lds(
        (const __attribute__((address_space(1))) unsigned int*)g,
        (__attribute__((address_space(3))) unsigned int*)l, 16, 0, 0);
}

enum { EPI_BFB = 0, EPI_VTB, EPI_PACK, EPI_PACK2, EPI_MASK, EPI_BF, EPI_OUT };

// ---------------------------------------------------------------------------
// gemmS: 128x128-tile m97-structure GEMM — VERBATIM round-5 text (fastest
// measured: 69.5us on the big pair). Instantiated ONLY twice (unpack EPI_BF,
// s2 EPI_MASK) to keep its codegen isolated from the other shapes (rule #19).
// ---------------------------------------------------------------------------
template<int EPI, bool CK, bool CS, bool SWZ, bool REVY>
__global__ __launch_bounds__(256)
void gemmS(const unsigned short* __restrict__ Aall, long a_sb, long a_sh, int lda,
           const unsigned short* __restrict__ Ball, long b_sb, long b_sh, int ldb,
           void* __restrict__ Oall, void* __restrict__ O2, long o_sb, long o_sh, int ldo,
           const float* __restrict__ bias, int bstride, int K, int NV)
{
    int bx, by, bz;
    if (SWZ) {   // grid must be (8,8,32)
        const int L = (int)blockIdx.x + ((int)blockIdx.y << 3) + ((int)blockIdx.z << 6);
        const int g = L & 7, r = L >> 3;
        bz = g + ((r >> 6) << 3);
        bx = r & 7;
        by = 7 - ((r >> 3) & 7);                 // longest-K first
    } else {
        bx = blockIdx.x;
        by = REVY ? (int)gridDim.y - 1 - (int)blockIdx.y : (int)blockIdx.y;
        bz = blockIdx.z;
    }
    const int m0 = by * 128, n0 = bx * 128;
    if (CS && n0 > m0 + 127) return;
    const int zb = bz >> 4, zh = bz & 15;
    const unsigned short* Ap = Aall + (long)zb * a_sb + (long)zh * a_sh;
    const unsigned short* Bp = Ball + (long)zb * b_sb + (long)zh * b_sh;
    const float* bi = bias + (long)zh * bstride;

    __shared__ alignas(16) unsigned short lA[128 * 64];
    __shared__ alignas(16) unsigned short lB[128 * 64];

    const int tid = threadIdx.x, w = tid >> 6, lane = tid & 63;
    const int lr = lane & 15, lg = lane >> 4;
    const int wm = (w >> 1) << 6, wn = (w & 1) << 6;

    const unsigned short* gA[4]; const unsigned short* gB[4]; int lo[4];
#pragma unroll
    for (int i = 0; i < 4; ++i) {
        const int q = (i * 4 + w) * 64 + lane, row = q >> 3, slot = q & 7;
        const int gs = (slot ^ (row & 7)) * 8;
        gA[i] = Ap + (long)(m0 + row) * lda + gs;
        int rb = n0 + row; if (rb >= NV) rb = NV - 1;
        gB[i] = Bp + (long)rb * ldb + gs;
        lo[i] = (i * 4 + w) * 512;
    }

    int abase[4], axor[4], bbase[4], bxor[4];
#pragma unroll
    for (int f = 0; f < 4; ++f) {
        const int ra = wm + f * 16 + lr;
        abase[f] = ra * 64; axor[f] = (ra & 7) * 8;
        const int rb = wn + f * 16 + lr;
        bbase[f] = rb * 64; bxor[f] = (rb & 7) * 8;
    }

    f32x4 acc[4][4] = {};
    const int Keff = CK ? ((K < m0 + 128) ? K : m0 + 128) : K;

    for (int k0 = 0; k0 < Keff; k0 += 64) {
#pragma unroll
        for (int i = 0; i < 4; ++i) {
            gload16(gA[i] + k0, &lA[lo[i]]);
            gload16(gB[i] + k0, &lB[lo[i]]);
        }
        __syncthreads();
#pragma unroll
        for (int kk = 0; kk < 64; kk += 32) {
            s16x8 af[4], bv[4];
#pragma unroll
            for (int f = 0; f < 4; ++f) {
                af[f] = *reinterpret_cast<const s16x8*>(&lA[abase[f] + ((kk + 8 * lg) ^ axor[f])]);
                bv[f] = *reinterpret_cast<const s16x8*>(&lB[bbase[f] + ((kk + 8 * lg) ^ bxor[f])]);
            }
#pragma unroll
            for (int fm = 0; fm < 4; ++fm)
#pragma unroll
                for (int fn = 0; fn < 4; ++fn)
                    acc[fm][fn] = __builtin_amdgcn_mfma_f32_16x16x32_bf16(af[fm], bv[fn], acc[fm][fn], 0, 0, 0);
        }
        __syncthreads();
    }

    const long obase = (long)zb * o_sb + (long)zh * o_sh;
#pragma unroll
    for (int fm = 0; fm < 4; ++fm)
#pragma unroll
        for (int fn = 0; fn < 4; ++fn) {
            const int t0 = m0 + wm + fm * 16 + lg * 4;
            const int gn = n0 + wn + fn * 16 + lr;
            if (gn >= NV) continue;
            if constexpr (EPI == EPI_PACK2) {             // dual store: P and P^T
                ushort4 pt;
                unsigned short* o1 = (unsigned short*)Oall;
                unsigned short* o2 = (unsigned short*)O2;
#pragma unroll
                for (int r = 0; r < 4; ++r) {
                    float vv = acc[fm][fn][r];
                    vv = vv > 0.f ? vv + 1.f : __expf(vv);   // elu(x)+1
                    const unsigned short b = f2bf(vv);
                    o1[obase + (long)(t0 + r) * ldo + gn] = b;
                    ((unsigned short*)&pt)[r] = b;
                }
                *reinterpret_cast<ushort4*>(&o2[obase + (long)gn * ldo + t0]) = pt;
            } else {
#pragma unroll
                for (int r = 0; r < 4; ++r) {
                    const int gm = t0 + r;
                    float vv = acc[fm][fn][r];
                    const long o = obase + (long)gm * ldo + gn;
                    if constexpr (EPI == EPI_BFB) {
                        ((unsigned short*)Oall)[o] = f2bf(vv + bi[gn]);
                    } else if constexpr (EPI == EPI_VTB) {
                        ((unsigned short*)Oall)[o] = f2bf(vv + bi[gm]);
                    } else if constexpr (EPI == EPI_PACK) {
                        vv = vv > 0.f ? vv + 1.f : __expf(vv);
                        ((unsigned short*)Oall)[o] = f2bf(vv);
                    } else if constexpr (EPI == EPI_MASK) {
                        vv = (gn <= gm) ? vv / (float)(gm + 1) : 0.f;
                        ((unsigned short*)Oall)[o] = f2bf(vv);
                    } else if constexpr (EPI == EPI_BF) {
                        ((unsigned short*)Oall)[o] = f2bf(vv);
                    } else { // EPI_OUT
                        ((float*)Oall)[o] = vv + bi[gn];
                    }
                }
            }
        }
}

// ---------------------------------------------------------------------------
// gemmT: TMxTN variant for the small GEMMs (projections, vhT, attn_out, out)
// ---------------------------------------------------------------------------
template<int TM, int TN, int EPI, bool CK, bool CS, bool REVY>
__global__ __launch_bounds__((TM/64)*(TN/64)*64)
void gemmT(const unsigned short* __restrict__ Aall, long a_sb, long a_sh, int lda,
           const unsigned short* __restrict__ Ball, long b_sb, long b_sh, int ldb,
           void* __restrict__ Oall, long o_sb, long o_sh, int ldo,
           const float* __restrict__ bias, int bstride, int K, int NV)
{
    constexpr int WN = TN / 64, WM = TM / 64, NWV = WM * WN, NTHR = NWV * 64;
    constexpr int IA = (TM * 8) / NTHR, IB = (TN * 8) / NTHR;

    const int bx = blockIdx.x;
    const int by = REVY ? (int)gridDim.y - 1 - (int)blockIdx.y : (int)blockIdx.y;
    const int bz = blockIdx.z;
    const int m0 = by * TM, n0 = bx * TN;
    if (CS && n0 > m0 + TM - 1) return;
    const int zb = bz >> 4, zh = bz & 15;
    const unsigned short* Ap = Aall + (long)zb * a_sb + (long)zh * a_sh;
    const unsigned short* Bp = Ball + (long)zb * b_sb + (long)zh * b_sh;
    const float* bi = bias + (long)zh * bstride;

    __shared__ alignas(16) unsigned short lA[TM * 64];
    __shared__ alignas(16) unsigned short lB[TN * 64];

    const int tid = threadIdx.x, w = tid >> 6, lane = tid & 63;
    const int lr = lane & 15, lg = lane >> 4;
    const int wm = (w / WN) * 64, wn = (w % WN) * 64;

    const unsigned short* gA[IA]; int loA[IA];
    const unsigned short* gB[IB]; int loB[IB];
#pragma unroll
    for (int i = 0; i < IA; ++i) {
        const int q = i * NTHR + tid, row = q >> 3, slot = q & 7;
        gA[i]  = Ap + (long)(m0 + row) * lda + ((slot ^ (row & 7)) * 8);
        loA[i] = (i * NWV + w) * 512;
    }
#pragma unroll
    for (int i = 0; i < IB; ++i) {
        const int q = i * NTHR + tid, row = q >> 3, slot = q & 7;
        int rb = n0 + row; if (rb >= NV) rb = NV - 1;
        gB[i]  = Bp + (long)rb * ldb + ((slot ^ (row & 7)) * 8);
        loB[i] = (i * NWV + w) * 512;
    }

    int abase[4], axor[4], bbase[4], bxor[4];
#pragma unroll
    for (int f = 0; f < 4; ++f) {
        const int ra = wm + f * 16 + lr;
        abase[f] = ra * 64; axor[f] = (ra & 7) * 8;
        const int rb = wn + f * 16 + lr;
        bbase[f] = rb * 64; bxor[f] = (rb & 7) * 8;
    }

    f32x4 acc[4][4] = {};
    const int Keff = CK ? ((K < m0 + TM) ? K : m0 + TM) : K;

    for (int k0 = 0; k0 < Keff; k0 += 64) {
#pragma unroll
        for (int i = 0; i < IA; ++i) gload16(gA[i] + k0, &lA[loA[i]]);
#pragma unroll
        for (int i = 0; i < IB; ++i) gload16(gB[i] + k0, &lB[loB[i]]);
        __syncthreads();
#pragma unroll
        for (int kk = 0; kk < 64; kk += 32) {
            s16x8 af[4], bv[4];
#pragma unroll
            for (int f = 0; f < 4; ++f) {
                af[f] = *reinterpret_cast<const s16x8*>(&lA[abase[f] + ((kk + 8 * lg) ^ axor[f])]);
                bv[f] = *reinterpret_cast<const s16x8*>(&lB[bbase[f] + ((kk + 8 * lg) ^ bxor[f])]);
            }
#pragma unroll
            for (int fm = 0; fm < 4; ++fm)
#pragma unroll
                for (int fn = 0; fn < 4; ++fn)
                    acc[fm][fn] = __builtin_amdgcn_mfma_f32_16x16x32_bf16(af[fm], bv[fn], acc[fm][fn], 0, 0, 0);
        }
        __syncthreads();
    }

    const long obase = (long)zb * o_sb + (long)zh * o_sh;
#pragma unroll
    for (int fm = 0; fm < 4; ++fm)
#pragma unroll
        for (int fn = 0; fn < 4; ++fn) {
            const int t0 = m0 + wm + fm * 16 + lg * 4;
            const int gn = n0 + wn + fn * 16 + lr;
            if (gn >= NV) continue;
#pragma unroll
            for (int r = 0; r < 4; ++r) {
                const int gm = t0 + r;
                float vv = acc[fm][fn][r];
                const long o = obase + (long)gm * ldo + gn;
                if constexpr (EPI == EPI_BFB) {
                    ((unsigned short*)Oall)[o] = f2bf(vv + bi[gn]);
                } else if constexpr (EPI == EPI_VTB) {
                    ((unsigned short*)Oall)[o] = f2bf(vv + bi[gm]);
                } else if constexpr (EPI == EPI_PACK) {
                    vv = vv > 0.f ? vv + 1.f : __expf(vv);
                    ((unsigned short*)Oall)[o] = f2bf(vv);
                } else if constexpr (EPI == EPI_MASK) {
                    vv = (gn <= gm) ? vv / (float)(gm + 1) : 0.f;
                    ((unsigned short*)Oall)[o] = f2bf(vv);
                } else if constexpr (EPI == EPI_BF) {
                    ((unsigned short*)Oall)[o] = f2bf(vv);
                } else { // EPI_OUT
                    ((float*)Oall)[o] = vv + bi[gn];
                }
            }
        }
}

// ---------------------------------------------------------------------------
// packsqk: merged pack2 + sQK (both 128x128-tile, K=64). Grid (8,8,64):
// z-swizzled so each head stays on one XCD; job = high bit (0: P/P^T dual
// store, 1: masked QK^T with causal block-skip).
// ---------------------------------------------------------------------------
__global__ __launch_bounds__(256)
void packsqk(const unsigned short* __restrict__ qh,
             const unsigned short* __restrict__ pbf,
             const unsigned short* __restrict__ kh,
             unsigned short* __restrict__ P, unsigned short* __restrict__ PT,
             unsigned short* __restrict__ SQ)
{
    const int L = (int)blockIdx.x + ((int)blockIdx.y << 3) + ((int)blockIdx.z << 6);
    const int g = L & 7, r = L >> 3;
    const int bzz = g + ((r >> 6) << 3);          // 0..63
    const int bx = r & 7, by = 7 - ((r >> 3) & 7);
    const int job = bzz >> 5, zz = bzz & 31;
    const int m0 = by * 128, n0 = bx * 128;
    if (job && n0 > m0 + 127) return;
    const int zb = zz >> 4, zh = zz & 15;
    const unsigned short* Ap = qh + (long)zb * SDM + zh * 64;
    const unsigned short* Bp = (job ? kh : pbf) + (long)zb * SDM + zh * 64;

    __shared__ alignas(16) unsigned short lA[128 * 64];
    __shared__ alignas(16) unsigned short lB[128 * 64];

    const int tid = threadIdx.x, w = tid >> 6, lane = tid & 63;
    const int lr = lane & 15, lg = lane >> 4;
    const int wm = (w >> 1) << 6, wn = (w & 1) << 6;

#pragma unroll
    for (int i = 0; i < 4; ++i) {
        const int q = i * 256 + tid, row = q >> 3, slot = q & 7;
        const int gs = (slot ^ (row & 7)) * 8;
        gload16(Ap + (long)(m0 + row) * DM + gs, &lA[(i * 4 + w) * 512]);
        gload16(Bp + (long)(n0 + row) * DM + gs, &lB[(i * 4 + w) * 512]);
    }
    __syncthreads();

    f32x4 acc[4][4] = {};
#pragma unroll
    for (int kk = 0; kk < 64; kk += 32) {
        s16x8 af[4], bv[4];
#pragma unroll
        for (int f = 0; f < 4; ++f) {
            const int ra = wm + f * 16 + lr;
            af[f] = *reinterpret_cast<const s16x8*>(&lA[ra * 64 + ((kk + 8 * lg) ^ ((ra & 7) * 8))]);
            const int rb = wn + f * 16 + lr;
            bv[f] = *reinterpret_cast<const s16x8*>(&lB[rb * 64 + ((kk + 8 * lg) ^ ((rb & 7) * 8))]);
        }
#pragma unroll
        for (int fm = 0; fm < 4; ++fm)
#pragma unroll
            for (int fn = 0; fn < 4; ++fn)
                acc[fm][fn] = __builtin_amdgcn_mfma_f32_16x16x32_bf16(af[fm], bv[fn], acc[fm][fn], 0, 0, 0);
    }

    const long obase = (long)zz * SS;
#pragma unroll
    for (int fm = 0; fm < 4; ++fm)
#pragma unroll
        for (int fn = 0; fn < 4; ++fn) {
            const int t0 = m0 + wm + fm * 16 + lg * 4;
            const int gn = n0 + wn + fn * 16 + lr;
            if (job == 0) {                        // P and P^T dual store
                ushort4 pt;
#pragma unroll
                for (int rr = 0; rr < 4; ++rr) {
                    float vv = acc[fm][fn][rr];
                    vv = vv > 0.f ? vv + 1.f : __expf(vv);
                    const unsigned short b = f2bf(vv);
                    P[obase + (long)(t0 + rr) * S + gn] = b;
                    ((unsigned short*)&pt)[rr] = b;
                }
                *reinterpret_cast<ushort4*>(&PT[obase + (long)gn * S + t0]) = pt;
            } else {                               // masked QK^T
#pragma unroll
                for (int rr = 0; rr < 4; ++rr) {
                    const int gm = t0 + rr;
                    float vv = acc[fm][fn][rr];
                    vv = (gn <= gm) ? vv / (float)(gm + 1) : 0.f;
                    SQ[obase + (long)gm * S + gn] = f2bf(vv);
                }
            }
        }
}

// wave-per-row softmax: 4 rows/block, no cross-wave sync; 32 B/lane loads
__global__ __launch_bounds__(256)
void softmax_rows(const unsigned short* __restrict__ in, unsigned short* __restrict__ out)
{
    const int w = threadIdx.x >> 6, lane = threadIdx.x & 63;
    const long row = (long)blockIdx.x * 4 + w;
    const u32x4* r4 = reinterpret_cast<const u32x4*>(in + row * S);
    u32x4 a = r4[lane * 2], b = r4[lane * 2 + 1];
    float v[16];
#pragma unroll
    for (int i = 0; i < 4; ++i) {
        v[2*i]     = bf2f((unsigned short)(a[i] & 0xFFFF));
        v[2*i+1]   = bf2f((unsigned short)(a[i] >> 16));
        v[8+2*i]   = bf2f((unsigned short)(b[i] & 0xFFFF));
        v[8+2*i+1] = bf2f((unsigned short)(b[i] >> 16));
    }
    float mx = v[0];
#pragma unroll
    for (int i = 1; i < 16; ++i) mx = fmaxf(mx, v[i]);
#pragma unroll
    for (int off = 32; off; off >>= 1) mx = fmaxf(mx, __shfl_xor(mx, off));
    float e[16], s = 0.f;
#pragma unroll
    for (int i = 0; i < 16; ++i) { e[i] = __expf(v[i] - mx); s += e[i]; }
#pragma unroll
    for (int off = 32; off; off >>= 1) s += __shfl_xor(s, off);
    const float inv = 1.f / s;
    u32x4 oa, ob;
#pragma unroll
    for (int i = 0; i < 4; ++i) {
        oa[i] = (unsigned)f2bf(e[2*i]   * inv) | ((unsigned)f2bf(e[2*i+1]   * inv) << 16);
        ob[i] = (unsigned)f2bf(e[8+2*i] * inv) | ((unsigned)f2bf(e[8+2*i+1] * inv) << 16);
    }
    u32x4* o4 = reinterpret_cast<u32x4*>(out + row * S);
    o4[lane * 2] = oa; o4[lane * 2 + 1] = ob;
}

// ---------------------------------------------------------------------------
// prep: merged input casts (z=0..3), weight transposes (z=4..7), bias pack (z=8)
// grid (2048, 1, 9) x 256 threads
// ---------------------------------------------------------------------------
__global__ __launch_bounds__(256)
void prep(const float* __restrict__ q_in, const float* __restrict__ k_in,
          const float* __restrict__ v_in, const float* __restrict__ p_in,
          const float* __restrict__ wq, const float* __restrict__ wk,
          const float* __restrict__ wv, const float* __restrict__ wc,
          const float* __restrict__ wqb, const float* __restrict__ wkb,
          unsigned short* __restrict__ qbf, unsigned short* __restrict__ wqT,
          float* __restrict__ bq2, int n4)
{
    const int z = blockIdx.z, bx = blockIdx.x, tid = threadIdx.x;
    if (z < 4) {
        const int i = bx * 256 + tid;
        if (i >= n4) return;
        const float* s = (z == 0) ? q_in : (z == 1) ? k_in : (z == 2) ? v_in : p_in;
        float4 x = reinterpret_cast<const float4*>(s)[i];
        ushort4 o; o.x = f2bf(x.x); o.y = f2bf(x.y); o.z = f2bf(x.z); o.w = f2bf(x.w);
        reinterpret_cast<ushort4*>(qbf + (size_t)z * n4 * 4)[i] = o;
    } else if (z < 8) {
        if (bx >= 256) return;
        __shared__ unsigned short t[64][72];
        const int zz = z - 4;
        const float* src = (zz == 0) ? wq : (zz == 1) ? wk : (zz == 2) ? wv : wc;
        const float scale = (zz == 0) ? 0.125f : 1.0f;
        unsigned short* dst = wqT + (size_t)zz * DM * DM;
        const int r0 = (bx >> 4) * 64, c0 = (bx & 15) * 64;
        const int lrow = tid >> 2, lseg = (tid & 3) << 4;
        const float4* g4 = reinterpret_cast<const float4*>(src + (long)(r0 + lrow) * DM + c0 + lseg);
        alignas(16) unsigned short tmp[16];
#pragma unroll
        for (int qq = 0; qq < 4; ++qq) {
            float4 x = g4[qq];
            tmp[4*qq+0] = f2bf(x.x * scale); tmp[4*qq+1] = f2bf(x.y * scale);
            tmp[4*qq+2] = f2bf(x.z * scale); tmp[4*qq+3] = f2bf(x.w * scale);
        }
#pragma unroll
        for (int j = 0; j < 16; ++j) t[lrow][lseg + j] = tmp[j];
        __syncthreads();
#pragma unroll
        for (int j = 0; j < 16; ++j) tmp[j] = t[lseg + j][lrow];
        unsigned short* d = dst + (long)(c0 + lrow) * DM + r0 + lseg;
        *reinterpret_cast<u32x4*>(d)     = *reinterpret_cast<const u32x4*>(tmp);
        *reinterpret_cast<u32x4*>(d + 8) = *reinterpret_cast<const u32x4*>(tmp + 8);
    } else {
        if (bx >= 4) return;
        const int i = bx * 256 + tid;
        if (i < DM) { bq2[i] = wqb[i] * 0.125f; bq2[DM + i] = wkb[i]; }
    }
}

extern "C" void kernel_launch(void* const* d_in, const int* in_sizes, int n_in,
                              void* d_out, int out_size, void* d_ws, size_t ws_size,
                              hipStream_t stream)
{
    (void)in_sizes; (void)n_in; (void)out_size;
    const float* v_in = (const float*)d_in[0];
    const float* k_in = (const float*)d_in[1];
    const float* q_in = (const float*)d_in[2];
    const float* p_in = (const float*)d_in[3];
    const float* wq   = (const float*)d_in[4];
    const float* wqb  = (const float*)d_in[5];
    const float* wk   = (const float*)d_in[6];
    const float* wkb  = (const float*)d_in[7];
    const float* wvw  = (const float*)d_in[8];
    const float* wvb  = (const float*)d_in[9];
    const float* wc   = (const float*)d_in[10];
    const float* wcb  = (const float*)d_in[11];
    float* out = (float*)d_out;

    char* ws = (char*)d_ws;
    size_t off = 0;
    auto take = [&](size_t n) { char* p = ws + off; off += (n + 255) & ~(size_t)255; return p; };
    unsigned short* qbf = (unsigned short*)take((size_t)BS * DM * 2);  // qbf..pbf contiguous
    unsigned short* kbf = (unsigned short*)take((size_t)BS * DM * 2);
    unsigned short* vbf = (unsigned short*)take((size_t)BS * DM * 2);
    unsigned short* pbf = (unsigned short*)take((size_t)BS * DM * 2);
    unsigned short* wqT = (unsigned short*)take((size_t)DM * DM * 2);  // wqT..wcT contiguous
    unsigned short* wkT = (unsigned short*)take((size_t)DM * DM * 2);
    unsigned short* wvT = (unsigned short*)take((size_t)DM * DM * 2);
    unsigned short* wcT = (unsigned short*)take((size_t)DM * DM * 2);
    float*          bq2 = (float*)take((size_t)2 * DM * 4);
    unsigned short* qh  = (unsigned short*)take((size_t)BS * DM * 2);  // qh,kh contiguous
    unsigned short* kh  = (unsigned short*)take((size_t)BS * DM * 2);
    unsigned short* vhT = (unsigned short*)take((size_t)BS * DM * 2);
    unsigned short* ao  = (unsigned short*)take((size_t)BS * DM * 2);
    const size_t ssz = (size_t)NB * HSS * 2;
    unsigned short* B1 = (unsigned short*)take(ssz);
    unsigned short* B2 = (unsigned short*)take(ssz);
    unsigned short* B3 = (unsigned short*)take(ssz);
    const bool dual = (ws_size >= off + ssz);          // 4th S x S buffer fits?
    unsigned short* B4 = dual ? (unsigned short*)take(ssz) : nullptr;
    (void)kbf; (void)wkT;

    const int n4 = BS * DM / 4;
    const dim3 b256(256), b128(128);

    prep<<<dim3(n4 / 256, 1, 9), b256, 0, stream>>>(
        q_in, k_in, v_in, p_in, wq, wk, wvw, wc, wqb, wkb, qbf, wqT, bq2, n4);

    // q,k projections merged over z (alpha folded into wqT/bq2), 64x128 tiles
    gemmT<64,128,EPI_BFB,false,false,false><<<dim3(8, 32, 2), b128, 0, stream>>>(
        qbf, 0, (long)BS*DM, DM,  wqT, 0, (long)DM*DM, DM,  qh, 0, (long)BS*DM, DM,
        bq2, DM, DM, DM);
    // vhT[b][dm][t] = (v@wv + b)^T, 64x128 tiles
    gemmT<64,128,EPI_VTB,false,false,false><<<dim3(8, 16, 2), b128, 0, stream>>>(
        wvT, 0, 0, DM,  vbf, 0, SDM, DM,  vhT, 0, (long)DM*S, S,
        wvb, 0, DM, S);

    unsigned short *pbuf, *ptbuf, *sqkbuf, *lbuf, *smbuf, *s2buf;
    if (dual) {
        // merged: P -> B1, P^T -> B2, sQK -> B3 in ONE launch
        packsqk<<<dim3(8, 8, 64), b256, 0, stream>>>(qh, pbf, kh, B1, B2, B3);
        pbuf = B1; ptbuf = B2; sqkbuf = B3; lbuf = B4; smbuf = B3; s2buf = B2;
    } else {
        // packT -> B1 ; sQK -> B2
        gemmT<128,128,EPI_PACK,false,false,false><<<dim3(8, 8, 32), b256, 0, stream>>>(
            pbf, SDM, 64, DM,  qh, SDM, 64, DM,  B1, HSS, SS, S,  wvb, 0, 64, S);
        gemmT<128,128,EPI_MASK,false,true,true><<<dim3(8, 8, 32), b256, 0, stream>>>(
            qh, SDM, 64, DM,  kh, SDM, 64, DM,  B2, HSS, SS, S,  wvb, 0, 64, S);
        ptbuf = B1; sqkbuf = B2; lbuf = B3; smbuf = B2; pbuf = B1; s2buf = B3;
    }
    // unpack (logits) = sQK @ P  (B = P^T rows j), causal-K -> lbuf (bf16)
    gemmS<EPI_BF,true,false,true,false><<<dim3(8, 8, 32), b256, 0, stream>>>(
        sqkbuf, HSS, SS, S,  ptbuf, HSS, SS, S,  lbuf, nullptr, HSS, SS, S,  wvb, 0, S, S);
    // softmax: lbuf -> smbuf (sQK dead)
    softmax_rows<<<dim3(NB*H*S/4), b256, 0, stream>>>(lbuf, smbuf);
    if (!dual) {
        // pack[t][s] = elu(qh.ph)+1 -> B1 (packT dead)
        gemmT<128,128,EPI_PACK,false,false,false><<<dim3(8, 8, 32), b256, 0, stream>>>(
            qh, SDM, 64, DM,  pbf, SDM, 64, DM,  B1, HSS, SS, S,  wvb, 0, 64, S);
    }
    // s2[t][s] = (sm . P[s,:]) * tril/(t+1)  (full K) -> s2buf (PT / logits dead)
    gemmS<EPI_MASK,false,true,true,false><<<dim3(8, 8, 32), b256, 0, stream>>>(
        smbuf, HSS, SS, S,  pbuf, HSS, SS, S,  s2buf, nullptr, HSS, SS, S,  wvb, 0, S, S);
    // attn_out[t][d] = s2 @ vh (B = vhT head-slice [d][s]), 128x64 tiles, causal-K
    gemmT<128,64,EPI_BF,true,false,true><<<dim3(1, 8, 32), b128, 0, stream>>>(
        s2buf, HSS, SS, S,  vhT, (long)DM*S, (long)64*S, S,  ao, SDM, 64, DM,
        wvb, 0, S, 64);
    // out = ao @ wc + b (f32), 64x128 tiles
    gemmT<64,128,EPI_OUT,false,false,false><<<dim3(8, 32, 1), b128, 0, stream>>>(
        ao, 0, 0, DM,  wcT, 0, 0, DM,  out, 0, 0, DM,  wcb, 0, DM, DM);
}

// Round 10
// 315.572 us; speedup vs baseline: 1.0124x; 1.0124x over previous
//
#include <hip/hip_runtime.h>

#define DEVI static __device__ __forceinline__

using s16x8 = __attribute__((ext_vector_type(8))) short;
using f32x4 = __attribute__((ext_vector_type(4))) float;
using u32x4 = __attribute__((ext_vector_type(4))) unsigned int;

static constexpr int H  = 16;
static constexpr int S  = 1024;
static constexpr int DM = 1024;
static constexpr int NB = 2;          // batch
static constexpr int BS = NB * S;     // 2048
static constexpr long SS  = (long)S * S;
static constexpr long HSS = (long)H * SS;
static constexpr long SDM = (long)S * DM;

DEVI unsigned short f2bf(float f) {
    union { float f; unsigned u; } c; c.f = f;
    c.u += 0x7FFFu + ((c.u >> 16) & 1u);   // RNE
    return (unsigned short)(c.u >> 16);
}
DEVI float bf2f(unsigned short v) {
    union { unsigned u; float f; } c; c.u = ((unsigned)v) << 16;
    return c.f;
}

// async global->LDS, 16 bytes per lane; lds dest = wave-uniform base + lane*16
DEVI void gload16(const unsigned short* g, unsigned short* l) {
    __builtin_amdgcn_global_load_lds(
        (const __attribute__((address_space(1))) unsigned int*)g,
        (__attribute__((address_space(3))) unsigned int*)l, 16, 0, 0);
}

enum { EPI_BFB = 0, EPI_VTB, EPI_PACK, EPI_MASK, EPI_BF, EPI_OUT };

// ---------------------------------------------------------------------------
// gemmE: dedicated unpack kernel — hot-pair body (verbatim round-5/9 loop) +
// EXP epilogue with fused row-sum atomics. E = exp(sQK @ P^T-rows), causal-K.
// Grid (8,8,32), XCD z-group swizzle + longest-K-first. Plain function: no
// shared-template codegen perturbation (rule #19).
// ---------------------------------------------------------------------------
__global__ __launch_bounds__(256)
void gemmE(const unsigned short* __restrict__ Aall,
           const unsigned short* __restrict__ Ball,
           unsigned short* __restrict__ Oall, float* __restrict__ sums)
{
    const int L = (int)blockIdx.x + ((int)blockIdx.y << 3) + ((int)blockIdx.z << 6);
    const int g = L & 7, r = L >> 3;
    const int bz = g + ((r >> 6) << 3);
    const int bx = r & 7;
    const int by = 7 - ((r >> 3) & 7);           // longest-K first
    const int m0 = by * 128, n0 = bx * 128;
    const unsigned short* Ap = Aall + (long)bz * SS;
    const unsigned short* Bp = Ball + (long)bz * SS;

    __shared__ alignas(16) unsigned short lA[128 * 64];
    __shared__ alignas(16) unsigned short lB[128 * 64];

    const int tid = threadIdx.x, w = tid >> 6, lane = tid & 63;
    const int lr = lane & 15, lg = lane >> 4;
    const int wm = (w >> 1) << 6, wn = (w & 1) << 6;

    const unsigned short* gA[4]; const unsigned short* gB[4]; int lo[4];
#pragma unroll
    for (int i = 0; i < 4; ++i) {
        const int q = (i * 4 + w) * 64 + lane, row = q >> 3, slot = q & 7;
        const int gs = (slot ^ (row & 7)) * 8;
        gA[i] = Ap + (long)(m0 + row) * S + gs;
        gB[i] = Bp + (long)(n0 + row) * S + gs;
        lo[i] = (i * 4 + w) * 512;
    }

    int abase[4], axor[4], bbase[4], bxor[4];
#pragma unroll
    for (int f = 0; f < 4; ++f) {
        const int ra = wm + f * 16 + lr;
        abase[f] = ra * 64; axor[f] = (ra & 7) * 8;
        const int rb = wn + f * 16 + lr;
        bbase[f] = rb * 64; bxor[f] = (rb & 7) * 8;
    }

    f32x4 acc[4][4] = {};
    const int Keff = m0 + 128;                   // causal-K cap (< S always)

    for (int k0 = 0; k0 < Keff; k0 += 64) {
#pragma unroll
        for (int i = 0; i < 4; ++i) {
            gload16(gA[i] + k0, &lA[lo[i]]);
            gload16(gB[i] + k0, &lB[lo[i]]);
        }
        __syncthreads();
#pragma unroll
        for (int kk = 0; kk < 64; kk += 32) {
            s16x8 af[4], bv[4];
#pragma unroll
            for (int f = 0; f < 4; ++f) {
                af[f] = *reinterpret_cast<const s16x8*>(&lA[abase[f] + ((kk + 8 * lg) ^ axor[f])]);
                bv[f] = *reinterpret_cast<const s16x8*>(&lB[bbase[f] + ((kk + 8 * lg) ^ bxor[f])]);
            }
#pragma unroll
            for (int fm = 0; fm < 4; ++fm)
#pragma unroll
                for (int fn = 0; fn < 4; ++fn)
                    acc[fm][fn] = __builtin_amdgcn_mfma_f32_16x16x32_bf16(af[fm], bv[fn], acc[fm][fn], 0, 0, 0);
        }
        __syncthreads();
    }

    const long obase = (long)bz * SS;
#pragma unroll
    for (int fm = 0; fm < 4; ++fm) {
        const int t0 = m0 + wm + fm * 16 + lg * 4;
        float es[4] = {0.f, 0.f, 0.f, 0.f};
#pragma unroll
        for (int fn = 0; fn < 4; ++fn) {
            const int gn = n0 + wn + fn * 16 + lr;
#pragma unroll
            for (int rr = 0; rr < 4; ++rr) {
                const float e = __expf(acc[fm][fn][rr]);
                Oall[obase + (long)(t0 + rr) * S + gn] = f2bf(e);
                es[rr] += e;
            }
        }
#pragma unroll
        for (int rr = 0; rr < 4; ++rr) {
            float s = es[rr];
            s += __shfl_xor(s, 1); s += __shfl_xor(s, 2);
            s += __shfl_xor(s, 4); s += __shfl_xor(s, 8);
            if (lr == 0) atomicAdd(&sums[(long)bz * S + t0 + rr], s);
        }
    }
}

// ---------------------------------------------------------------------------
// gemmZ: dedicated s2 kernel — hot-pair body verbatim + fused softmax-
// normalize + causal mask epilogue: s2 = (E.P) / (sums[t]*(t+1)), blocks with
// n0 > m0+127 skipped. Grid (8,8,32), same swizzle. Plain function.
// ---------------------------------------------------------------------------
__global__ __launch_bounds__(256)
void gemmZ(const unsigned short* __restrict__ Aall,
           const unsigned short* __restrict__ Ball,
           unsigned short* __restrict__ Oall, const float* __restrict__ sums)
{
    const int L = (int)blockIdx.x + ((int)blockIdx.y << 3) + ((int)blockIdx.z << 6);
    const int g = L & 7, r = L >> 3;
    const int bz = g + ((r >> 6) << 3);
    const int bx = r & 7;
    const int by = 7 - ((r >> 3) & 7);
    const int m0 = by * 128, n0 = bx * 128;
    if (n0 > m0 + 127) return;
    const unsigned short* Ap = Aall + (long)bz * SS;
    const unsigned short* Bp = Ball + (long)bz * SS;

    __shared__ alignas(16) unsigned short lA[128 * 64];
    __shared__ alignas(16) unsigned short lB[128 * 64];

    const int tid = threadIdx.x, w = tid >> 6, lane = tid & 63;
    const int lr = lane & 15, lg = lane >> 4;
    const int wm = (w >> 1) << 6, wn = (w & 1) << 6;

    const unsigned short* gA[4]; const unsigned short* gB[4]; int lo[4];
#pragma unroll
    for (int i = 0; i < 4; ++i) {
        const int q = (i * 4 + w) * 64 + lane, row = q >> 3, slot = q & 7;
        const int gs = (slot ^ (row & 7)) * 8;
        gA[i] = Ap + (long)(m0 + row) * S + gs;
        gB[i] = Bp + (long)(n0 + row) * S + gs;
        lo[i] = (i * 4 + w) * 512;
    }

    int abase[4], axor[4], bbase[4], bxor[4];
#pragma unroll
    for (int f = 0; f < 4; ++f) {
        const int ra = wm + f * 16 + lr;
        abase[f] = ra * 64; axor[f] = (ra & 7) * 8;
        const int rb = wn + f * 16 + lr;
        bbase[f] = rb * 64; bxor[f] = (rb & 7) * 8;
    }

    f32x4 acc[4][4] = {};

    for (int k0 = 0; k0 < S; k0 += 64) {
#pragma unroll
        for (int i = 0; i < 4; ++i) {
            gload16(gA[i] + k0, &lA[lo[i]]);
            gload16(gB[i] + k0, &lB[lo[i]]);
        }
        __syncthreads();
#pragma unroll
        for (int kk = 0; kk < 64; kk += 32) {
            s16x8 af[4], bv[4];
#pragma unroll
            for (int f = 0; f < 4; ++f) {
                af[f] = *reinterpret_cast<const s16x8*>(&lA[abase[f] + ((kk + 8 * lg) ^ axor[f])]);
                bv[f] = *reinterpret_cast<const s16x8*>(&lB[bbase[f] + ((kk + 8 * lg) ^ bxor[f])]);
            }
#pragma unroll
            for (int fm = 0; fm < 4; ++fm)
#pragma unroll
                for (int fn = 0; fn < 4; ++fn)
                    acc[fm][fn] = __builtin_amdgcn_mfma_f32_16x16x32_bf16(af[fm], bv[fn], acc[fm][fn], 0, 0, 0);
        }
        __syncthreads();
    }

    const long obase = (long)bz * SS;
#pragma unroll
    for (int fm = 0; fm < 4; ++fm) {
        const int t0 = m0 + wm + fm * 16 + lg * 4;
        float rec[4];
#pragma unroll
        for (int rr = 0; rr < 4; ++rr)
            rec[rr] = 1.f / (sums[(long)bz * S + t0 + rr] * (float)(t0 + rr + 1));
#pragma unroll
        for (int fn = 0; fn < 4; ++fn) {
            const int gn = n0 + wn + fn * 16 + lr;
#pragma unroll
            for (int rr = 0; rr < 4; ++rr) {
                const int gm = t0 + rr;
                const float vv = (gn <= gm) ? acc[fm][fn][rr] * rec[rr] : 0.f;
                Oall[obase + (long)gm * S + gn] = f2bf(vv);
            }
        }
    }
}

// ---------------------------------------------------------------------------
// gemmT: TMxTN variant for the small GEMMs (projections, vhT, attn_out, out)
// ---------------------------------------------------------------------------
template<int TM, int TN, int EPI, bool CK, bool CS, bool REVY>
__global__ __launch_bounds__((TM/64)*(TN/64)*64)
void gemmT(const unsigned short* __restrict__ Aall, long a_sb, long a_sh, int lda,
           const unsigned short* __restrict__ Ball, long b_sb, long b_sh, int ldb,
           void* __restrict__ Oall, long o_sb, long o_sh, int ldo,
           const float* __restrict__ bias, int bstride, int K, int NV)
{
    constexpr int WN = TN / 64, WM = TM / 64, NWV = WM * WN, NTHR = NWV * 64;
    constexpr int IA = (TM * 8) / NTHR, IB = (TN * 8) / NTHR;
    constexpr int IMX = IA > IB ? IA : IB;

    const int bx = blockIdx.x;
    const int by = REVY ? (int)gridDim.y - 1 - (int)blockIdx.y : (int)blockIdx.y;
    const int bz = blockIdx.z;
    const int m0 = by * TM, n0 = bx * TN;
    if (CS && n0 > m0 + TM - 1) return;
    const int zb = bz >> 4, zh = bz & 15;
    const unsigned short* Ap = Aall + (long)zb * a_sb + (long)zh * a_sh;
    const unsigned short* Bp = Ball + (long)zb * b_sb + (long)zh * b_sh;
    const float* bi = bias + (long)zh * bstride;

    __shared__ alignas(16) unsigned short lA[TM * 64];
    __shared__ alignas(16) unsigned short lB[TN * 64];

    const int tid = threadIdx.x, w = tid >> 6, lane = tid & 63;
    const int lr = lane & 15, lg = lane >> 4;
    const int wm = (w / WN) * 64, wn = (w % WN) * 64;

    const unsigned short* gA[IA]; int loA[IA];
    const unsigned short* gB[IB]; int loB[IB];
#pragma unroll
    for (int i = 0; i < IA; ++i) {
        const int q = i * NTHR + tid, row = q >> 3, slot = q & 7;
        gA[i]  = Ap + (long)(m0 + row) * lda + ((slot ^ (row & 7)) * 8);
        loA[i] = (i * NWV + w) * 512;
    }
#pragma unroll
    for (int i = 0; i < IB; ++i) {
        const int q = i * NTHR + tid, row = q >> 3, slot = q & 7;
        int rb = n0 + row; if (rb >= NV) rb = NV - 1;
        gB[i]  = Bp + (long)rb * ldb + ((slot ^ (row & 7)) * 8);
        loB[i] = (i * NWV + w) * 512;
    }

    int abase[4], axor[4], bbase[4], bxor[4];
#pragma unroll
    for (int f = 0; f < 4; ++f) {
        const int ra = wm + f * 16 + lr;
        abase[f] = ra * 64; axor[f] = (ra & 7) * 8;
        const int rb = wn + f * 16 + lr;
        bbase[f] = rb * 64; bxor[f] = (rb & 7) * 8;
    }

    f32x4 acc[4][4] = {};
    const int Keff = CK ? ((K < m0 + TM) ? K : m0 + TM) : K;

    for (int k0 = 0; k0 < Keff; k0 += 64) {
#pragma unroll
        for (int i = 0; i < IMX; ++i) {          // interleaved A/B issue order
            if (i < IA) gload16(gA[i] + k0, &lA[loA[i]]);
            if (i < IB) gload16(gB[i] + k0, &lB[loB[i]]);
        }
        __syncthreads();
#pragma unroll
        for (int kk = 0; kk < 64; kk += 32) {
            s16x8 af[4], bv[4];
#pragma unroll
            for (int f = 0; f < 4; ++f) {
                af[f] = *reinterpret_cast<const s16x8*>(&lA[abase[f] + ((kk + 8 * lg) ^ axor[f])]);
                bv[f] = *reinterpret_cast<const s16x8*>(&lB[bbase[f] + ((kk + 8 * lg) ^ bxor[f])]);
            }
#pragma unroll
            for (int fm = 0; fm < 4; ++fm)
#pragma unroll
                for (int fn = 0; fn < 4; ++fn)
                    acc[fm][fn] = __builtin_amdgcn_mfma_f32_16x16x32_bf16(af[fm], bv[fn], acc[fm][fn], 0, 0, 0);
        }
        __syncthreads();
    }

    const long obase = (long)zb * o_sb + (long)zh * o_sh;
#pragma unroll
    for (int fm = 0; fm < 4; ++fm)
#pragma unroll
        for (int fn = 0; fn < 4; ++fn) {
            const int t0 = m0 + wm + fm * 16 + lg * 4;
            const int gn = n0 + wn + fn * 16 + lr;
            if (gn >= NV) continue;
#pragma unroll
            for (int r = 0; r < 4; ++r) {
                const int gm = t0 + r;
                float vv = acc[fm][fn][r];
                const long o = obase + (long)gm * ldo + gn;
                if constexpr (EPI == EPI_BFB) {
                    ((unsigned short*)Oall)[o] = f2bf(vv + bi[gn]);
                } else if constexpr (EPI == EPI_VTB) {
                    ((unsigned short*)Oall)[o] = f2bf(vv + bi[gm]);
                } else if constexpr (EPI == EPI_PACK) {
                    vv = vv > 0.f ? vv + 1.f : __expf(vv);
                    ((unsigned short*)Oall)[o] = f2bf(vv);
                } else if constexpr (EPI == EPI_MASK) {
                    vv = (gn <= gm) ? vv / (float)(gm + 1) : 0.f;
                    ((unsigned short*)Oall)[o] = f2bf(vv);
                } else if constexpr (EPI == EPI_BF) {
                    ((unsigned short*)Oall)[o] = f2bf(vv);
                } else { // EPI_OUT
                    ((float*)Oall)[o] = vv + bi[gn];
                }
            }
        }
}

// ---------------------------------------------------------------------------
// packsqk: merged pack2 + sQK (both 128x128-tile, K=64). Grid (8,8,64):
// z-swizzled so each head stays on one XCD; job = high bit (0: P/P^T dual
// store, 1: masked QK^T with causal block-skip).
// ---------------------------------------------------------------------------
__global__ __launch_bounds__(256)
void packsqk(const unsigned short* __restrict__ qh,
             const unsigned short* __restrict__ pbf,
             const unsigned short* __restrict__ kh,
             unsigned short* __restrict__ P, unsigned short* __restrict__ PT,
             unsigned short* __restrict__ SQ)
{
    const int L = (int)blockIdx.x + ((int)blockIdx.y << 3) + ((int)blockIdx.z << 6);
    const int g = L & 7, r = L >> 3;
    const int bzz = g + ((r >> 6) << 3);          // 0..63
    const int bx = r & 7, by = 7 - ((r >> 3) & 7);
    const int job = bzz >> 5, zz = bzz & 31;
    const int m0 = by * 128, n0 = bx * 128;
    if (job && n0 > m0 + 127) return;
    const int zb = zz >> 4, zh = zz & 15;
    const unsigned short* Ap = qh + (long)zb * SDM + zh * 64;
    const unsigned short* Bp = (job ? kh : pbf) + (long)zb * SDM + zh * 64;

    __shared__ alignas(16) unsigned short lA[128 * 64];
    __shared__ alignas(16) unsigned short lB[128 * 64];

    const int tid = threadIdx.x, w = tid >> 6, lane = tid & 63;
    const int lr = lane & 15, lg = lane >> 4;
    const int wm = (w >> 1) << 6, wn = (w & 1) << 6;

#pragma unroll
    for (int i = 0; i < 4; ++i) {
        const int q = i * 256 + tid, row = q >> 3, slot = q & 7;
        const int gs = (slot ^ (row & 7)) * 8;
        gload16(Ap + (long)(m0 + row) * DM + gs, &lA[(i * 4 + w) * 512]);
        gload16(Bp + (long)(n0 + row) * DM + gs, &lB[(i * 4 + w) * 512]);
    }
    __syncthreads();

    f32x4 acc[4][4] = {};
#pragma unroll
    for (int kk = 0; kk < 64; kk += 32) {
        s16x8 af[4], bv[4];
#pragma unroll
        for (int f = 0; f < 4; ++f) {
            const int ra = wm + f * 16 + lr;
            af[f] = *reinterpret_cast<const s16x8*>(&lA[ra * 64 + ((kk + 8 * lg) ^ ((ra & 7) * 8))]);
            const int rb = wn + f * 16 + lr;
            bv[f] = *reinterpret_cast<const s16x8*>(&lB[rb * 64 + ((kk + 8 * lg) ^ ((rb & 7) * 8))]);
        }
#pragma unroll
        for (int fm = 0; fm < 4; ++fm)
#pragma unroll
            for (int fn = 0; fn < 4; ++fn)
                acc[fm][fn] = __builtin_amdgcn_mfma_f32_16x16x32_bf16(af[fm], bv[fn], acc[fm][fn], 0, 0, 0);
    }

    const long obase = (long)zz * SS;
#pragma unroll
    for (int fm = 0; fm < 4; ++fm)
#pragma unroll
        for (int fn = 0; fn < 4; ++fn) {
            const int t0 = m0 + wm + fm * 16 + lg * 4;
            const int gn = n0 + wn + fn * 16 + lr;
            if (job == 0) {                        // P and P^T dual store
                ushort4 pt;
#pragma unroll
                for (int rr = 0; rr < 4; ++rr) {
                    float vv = acc[fm][fn][rr];
                    vv = vv > 0.f ? vv + 1.f : __expf(vv);
                    const unsigned short b = f2bf(vv);
                    P[obase + (long)(t0 + rr) * S + gn] = b;
                    ((unsigned short*)&pt)[rr] = b;
                }
                *reinterpret_cast<ushort4*>(&PT[obase + (long)gn * S + t0]) = pt;
            } else {                               // masked QK^T
#pragma unroll
                for (int rr = 0; rr < 4; ++rr) {
                    const int gm = t0 + rr;
                    float vv = acc[fm][fn][rr];
                    vv = (gn <= gm) ? vv / (float)(gm + 1) : 0.f;
                    SQ[obase + (long)gm * S + gn] = f2bf(vv);
                }
            }
        }
}

// ---------------------------------------------------------------------------
// prep: merged input casts (z=0..3), weight transposes (z=4..7), bias pack (z=8)
// grid (2048, 1, 9) x 256 threads
// ---------------------------------------------------------------------------
__global__ __launch_bounds__(256)
void prep(const float* __restrict__ q_in, const float* __restrict__ k_in,
          const float* __restrict__ v_in, const float* __restrict__ p_in,
          const float* __restrict__ wq, const float* __restrict__ wk,
          const float* __restrict__ wv, const float* __restrict__ wc,
          const float* __restrict__ wqb, const float* __restrict__ wkb,
          unsigned short* __restrict__ qbf, unsigned short* __restrict__ wqT,
          float* __restrict__ bq2, int n4)
{
    const int z = blockIdx.z, bx = blockIdx.x, tid = threadIdx.x;
    if (z < 4) {
        const int i = bx * 256 + tid;
        if (i >= n4) return;
        const float* s = (z == 0) ? q_in : (z == 1) ? k_in : (z == 2) ? v_in : p_in;
        float4 x = reinterpret_cast<const float4*>(s)[i];
        ushort4 o; o.x = f2bf(x.x); o.y = f2bf(x.y); o.z = f2bf(x.z); o.w = f2bf(x.w);
        reinterpret_cast<ushort4*>(qbf + (size_t)z * n4 * 4)[i] = o;
    } else if (z < 8) {
        if (bx >= 256) return;
        __shared__ unsigned short t[64][72];
        const int zz = z - 4;
        const float* src = (zz == 0) ? wq : (zz == 1) ? wk : (zz == 2) ? wv : wc;
        const float scale = (zz == 0) ? 0.125f : 1.0f;
        unsigned short* dst = wqT + (size_t)zz * DM * DM;
        const int r0 = (bx >> 4) * 64, c0 = (bx & 15) * 64;
        const int lrow = tid >> 2, lseg = (tid & 3) << 4;
        const float4* g4 = reinterpret_cast<const float4*>(src + (long)(r0 + lrow) * DM + c0 + lseg);
        alignas(16) unsigned short tmp[16];
#pragma unroll
        for (int qq = 0; qq < 4; ++qq) {
            float4 x = g4[qq];
            tmp[4*qq+0] = f2bf(x.x * scale); tmp[4*qq+1] = f2bf(x.y * scale);
            tmp[4*qq+2] = f2bf(x.z * scale); tmp[4*qq+3] = f2bf(x.w * scale);
        }
#pragma unroll
        for (int j = 0; j < 16; ++j) t[lrow][lseg + j] = tmp[j];
        __syncthreads();
#pragma unroll
        for (int j = 0; j < 16; ++j) tmp[j] = t[lseg + j][lrow];
        unsigned short* d = dst + (long)(c0 + lrow) * DM + r0 + lseg;
        *reinterpret_cast<u32x4*>(d)     = *reinterpret_cast<const u32x4*>(tmp);
        *reinterpret_cast<u32x4*>(d + 8) = *reinterpret_cast<const u32x4*>(tmp + 8);
    } else {
        if (bx >= 4) return;
        const int i = bx * 256 + tid;
        if (i < DM) { bq2[i] = wqb[i] * 0.125f; bq2[DM + i] = wkb[i]; }
    }
}

extern "C" void kernel_launch(void* const* d_in, const int* in_sizes, int n_in,
                              void* d_out, int out_size, void* d_ws, size_t ws_size,
                              hipStream_t stream)
{
    (void)in_sizes; (void)n_in; (void)out_size;
    const float* v_in = (const float*)d_in[0];
    const float* k_in = (const float*)d_in[1];
    const float* q_in = (const float*)d_in[2];
    const float* p_in = (const float*)d_in[3];
    const float* wq   = (const float*)d_in[4];
    const float* wqb  = (const float*)d_in[5];
    const float* wk   = (const float*)d_in[6];
    const float* wkb  = (const float*)d_in[7];
    const float* wvw  = (const float*)d_in[8];
    const float* wvb  = (const float*)d_in[9];
    const float* wc   = (const float*)d_in[10];
    const float* wcb  = (const float*)d_in[11];
    float* out = (float*)d_out;

    char* ws = (char*)d_ws;
    size_t off = 0;
    auto take = [&](size_t n) { char* p = ws + off; off += (n + 255) & ~(size_t)255; return p; };
    unsigned short* qbf = (unsigned short*)take((size_t)BS * DM * 2);  // qbf..pbf contiguous
    unsigned short* kbf = (unsigned short*)take((size_t)BS * DM * 2);
    unsigned short* vbf = (unsigned short*)take((size_t)BS * DM * 2);
    unsigned short* pbf = (unsigned short*)take((size_t)BS * DM * 2);
    unsigned short* wqT = (unsigned short*)take((size_t)DM * DM * 2);  // wqT..wcT contiguous
    unsigned short* wkT = (unsigned short*)take((size_t)DM * DM * 2);
    unsigned short* wvT = (unsigned short*)take((size_t)DM * DM * 2);
    unsigned short* wcT = (unsigned short*)take((size_t)DM * DM * 2);
    float*          bq2 = (float*)take((size_t)2 * DM * 4);
    float*          sums= (float*)take((size_t)NB * H * S * 4);
    unsigned short* qh  = (unsigned short*)take((size_t)BS * DM * 2);  // qh,kh contiguous
    unsigned short* kh  = (unsigned short*)take((size_t)BS * DM * 2);
    unsigned short* vhT = (unsigned short*)take((size_t)BS * DM * 2);
    unsigned short* ao  = (unsigned short*)take((size_t)BS * DM * 2);
    const size_t ssz = (size_t)NB * HSS * 2;
    unsigned short* B1 = (unsigned short*)take(ssz);
    unsigned short* B2 = (unsigned short*)take(ssz);
    unsigned short* B3 = (unsigned short*)take(ssz);
    const bool dual = (ws_size >= off + ssz);          // 4th S x S buffer fits?
    unsigned short* B4 = dual ? (unsigned short*)take(ssz) : nullptr;
    (void)kbf; (void)wkT;

    const int n4 = BS * DM / 4;
    const dim3 b256(256), b128(128);

    hipMemsetAsync(sums, 0, (size_t)NB * H * S * 4, stream);
    prep<<<dim3(n4 / 256, 1, 9), b256, 0, stream>>>(
        q_in, k_in, v_in, p_in, wq, wk, wvw, wc, wqb, wkb, qbf, wqT, bq2, n4);

    // q,k projections merged over z (alpha folded into wqT/bq2), 64x128 tiles
    gemmT<64,128,EPI_BFB,false,false,false><<<dim3(8, 32, 2), b128, 0, stream>>>(
        qbf, 0, (long)BS*DM, DM,  wqT, 0, (long)DM*DM, DM,  qh, 0, (long)BS*DM, DM,
        bq2, DM, DM, DM);
    // vhT[b][dm][t] = (v@wv + b)^T, 64x128 tiles
    gemmT<64,128,EPI_VTB,false,false,false><<<dim3(8, 16, 2), b128, 0, stream>>>(
        wvT, 0, 0, DM,  vbf, 0, SDM, DM,  vhT, 0, (long)DM*S, S,
        wvb, 0, DM, S);

    unsigned short *pbuf, *ptbuf, *sqkbuf, *ebuf, *s2buf;
    if (dual) {
        // merged: P -> B1, P^T -> B2, sQK -> B3 in ONE launch
        packsqk<<<dim3(8, 8, 64), b256, 0, stream>>>(qh, pbf, kh, B1, B2, B3);
        pbuf = B1; ptbuf = B2; sqkbuf = B3; ebuf = B4; s2buf = B3;
    } else {
        // packT -> B1 ; sQK -> B2
        gemmT<128,128,EPI_PACK,false,false,false><<<dim3(8, 8, 32), b256, 0, stream>>>(
            pbf, SDM, 64, DM,  qh, SDM, 64, DM,  B1, HSS, SS, S,  wvb, 0, 64, S);
        gemmT<128,128,EPI_MASK,false,true,true><<<dim3(8, 8, 32), b256, 0, stream>>>(
            qh, SDM, 64, DM,  kh, SDM, 64, DM,  B2, HSS, SS, S,  wvb, 0, 64, S);
        ptbuf = B1; sqkbuf = B2; ebuf = B3; pbuf = B1; s2buf = B2;
    }
    // E = exp(sQK @ P) with fused row-sums, causal-K -> ebuf (bf16)
    gemmE<<<dim3(8, 8, 32), b256, 0, stream>>>(sqkbuf, ptbuf, ebuf, sums);
    if (!dual) {
        // pack[t][s] = elu(qh.ph)+1 -> B1 (packT dead)
        gemmT<128,128,EPI_PACK,false,false,false><<<dim3(8, 8, 32), b256, 0, stream>>>(
            qh, SDM, 64, DM,  pbf, SDM, 64, DM,  B1, HSS, SS, S,  wvb, 0, 64, S);
    }
    // s2[t][s] = (E[t,:].P[s,:]) / (sums[t]*(t+1)), causal-skip -> s2buf
    gemmZ<<<dim3(8, 8, 32), b256, 0, stream>>>(ebuf, pbuf, s2buf, sums);
    // attn_out[t][d] = s2 @ vh (B = vhT head-slice [d][s]), 128x64 tiles, causal-K
    gemmT<128,64,EPI_BF,true,false,true><<<dim3(1, 8, 32), b128, 0, stream>>>(
        s2buf, HSS, SS, S,  vhT, (long)DM*S, (long)64*S, S,  ao, SDM, 64, DM,
        wvb, 0, S, 64);
    // out = ao @ wc + b (f32), 64x128 tiles
    gemmT<64,128,EPI_OUT,false,false,false><<<dim3(8, 32, 1), b128, 0, stream>>>(
        ao, 0, 0, DM,  wcT, 0, 0, DM,  out, 0, 0, DM,  wcb, 0, DM, DM);
}

// Round 11
// 298.665 us; speedup vs baseline: 1.0697x; 1.0566x over previous
//
#include <hip/hip_runtime.h>

#define DEVI static __device__ __forceinline__

using s16x8 = __attribute__((ext_vector_type(8))) short;
using f32x4 = __attribute__((ext_vector_type(4))) float;
using u32x4 = __attribute__((ext_vector_type(4))) unsigned int;

static constexpr int H  = 16;
static constexpr int S  = 1024;
static constexpr int DM = 1024;
static constexpr int NB = 2;          // batch
static constexpr int BS = NB * S;     // 2048
static constexpr long SS  = (long)S * S;
static constexpr long HSS = (long)H * SS;
static constexpr long SDM = (long)S * DM;

DEVI unsigned short f2bf(float f) {
    union { float f; unsigned u; } c; c.f = f;
    c.u += 0x7FFFu + ((c.u >> 16) & 1u);   // RNE
    return (unsigned short)(c.u >> 16);
}
DEVI float bf2f(unsigned short v) {
    union { unsigned u; float f; } c; c.u = ((unsigned)v) << 16;
    return c.f;
}

// async global->LDS, 16 bytes per lane; lds dest = wave-uniform base + lane*16
DEVI void gload16(const unsigned short* g, unsigned short* l) {
    __builtin_amdgcn_global_load_lds(
        (const __attribute__((address_space(1))) unsigned int*)g,
        (__attribute__((address_space(3))) unsigned int*)l, 16, 0, 0);
}

enum { EPI_BFB = 0, EPI_VTB, EPI_PACK, EPI_PACK2, EPI_MASK, EPI_BF, EPI_OUT };

// ---------------------------------------------------------------------------
// gemmU: dedicated unpack kernel (plain function — rule #19 isolation).
// E = exp(sQK @ P^T-rows), causal-K capped. NO atomics (r10 lesson: -6.5us).
// Grid (8,8,32): XCD z-group swizzle + longest-K-first.
// ---------------------------------------------------------------------------
__global__ __launch_bounds__(256)
void gemmU(const unsigned short* __restrict__ Aall,
           const unsigned short* __restrict__ Ball,
           unsigned short* __restrict__ Oall)
{
    const int L = (int)blockIdx.x + ((int)blockIdx.y << 3) + ((int)blockIdx.z << 6);
    const int g = L & 7, r = L >> 3;
    const int bz = g + ((r >> 6) << 3);
    const int bx = r & 7;
    const int by = 7 - ((r >> 3) & 7);           // longest-K first
    const int m0 = by * 128, n0 = bx * 128;
    const unsigned short* Ap = Aall + (long)bz * SS;
    const unsigned short* Bp = Ball + (long)bz * SS;

    __shared__ alignas(16) unsigned short lA[128 * 64];
    __shared__ alignas(16) unsigned short lB[128 * 64];

    const int tid = threadIdx.x, w = tid >> 6, lane = tid & 63;
    const int lr = lane & 15, lg = lane >> 4;
    const int wm = (w >> 1) << 6, wn = (w & 1) << 6;

    const unsigned short* gA[4]; const unsigned short* gB[4]; int lo[4];
#pragma unroll
    for (int i = 0; i < 4; ++i) {
        const int q = (i * 4 + w) * 64 + lane, row = q >> 3, slot = q & 7;
        const int gs = (slot ^ (row & 7)) * 8;
        gA[i] = Ap + (long)(m0 + row) * S + gs;
        gB[i] = Bp + (long)(n0 + row) * S + gs;
        lo[i] = (i * 4 + w) * 512;
    }

    int abase[4], axor[4], bbase[4], bxor[4];
#pragma unroll
    for (int f = 0; f < 4; ++f) {
        const int ra = wm + f * 16 + lr;
        abase[f] = ra * 64; axor[f] = (ra & 7) * 8;
        const int rb = wn + f * 16 + lr;
        bbase[f] = rb * 64; bxor[f] = (rb & 7) * 8;
    }

    f32x4 acc[4][4] = {};
    const int Keff = m0 + 128;                   // causal-K cap

    for (int k0 = 0; k0 < Keff; k0 += 64) {
#pragma unroll
        for (int i = 0; i < 4; ++i) {
            gload16(gA[i] + k0, &lA[lo[i]]);
            gload16(gB[i] + k0, &lB[lo[i]]);
        }
        __syncthreads();
#pragma unroll
        for (int kk = 0; kk < 64; kk += 32) {
            s16x8 af[4], bv[4];
#pragma unroll
            for (int f = 0; f < 4; ++f) {
                af[f] = *reinterpret_cast<const s16x8*>(&lA[abase[f] + ((kk + 8 * lg) ^ axor[f])]);
                bv[f] = *reinterpret_cast<const s16x8*>(&lB[bbase[f] + ((kk + 8 * lg) ^ bxor[f])]);
            }
#pragma unroll
            for (int fm = 0; fm < 4; ++fm)
#pragma unroll
                for (int fn = 0; fn < 4; ++fn)
                    acc[fm][fn] = __builtin_amdgcn_mfma_f32_16x16x32_bf16(af[fm], bv[fn], acc[fm][fn], 0, 0, 0);
        }
        __syncthreads();
    }

    const long obase = (long)bz * SS;
#pragma unroll
    for (int fm = 0; fm < 4; ++fm)
#pragma unroll
        for (int fn = 0; fn < 4; ++fn) {
            const int t0 = m0 + wm + fm * 16 + lg * 4;
            const int gn = n0 + wn + fn * 16 + lr;
#pragma unroll
            for (int rr = 0; rr < 4; ++rr)
                Oall[obase + (long)(t0 + rr) * S + gn] = f2bf(__expf(acc[fm][fn][rr]));
        }
}

// ---------------------------------------------------------------------------
// gemmV: dedicated s2 kernel (plain function). s2 = (E.P) * inv2[t], masked;
// inv2[t] = 1/(rowsum(E)*(t+1)) precomputed. Causal block-skip. Grid (8,8,32).
// ---------------------------------------------------------------------------
__global__ __launch_bounds__(256)
void gemmV(const unsigned short* __restrict__ Aall,
           const unsigned short* __restrict__ Ball,
           unsigned short* __restrict__ Oall, const float* __restrict__ inv2)
{
    const int L = (int)blockIdx.x + ((int)blockIdx.y << 3) + ((int)blockIdx.z << 6);
    const int g = L & 7, r = L >> 3;
    const int bz = g + ((r >> 6) << 3);
    const int bx = r & 7;
    const int by = 7 - ((r >> 3) & 7);
    const int m0 = by * 128, n0 = bx * 128;
    if (n0 > m0 + 127) return;
    const unsigned short* Ap = Aall + (long)bz * SS;
    const unsigned short* Bp = Ball + (long)bz * SS;

    __shared__ alignas(16) unsigned short lA[128 * 64];
    __shared__ alignas(16) unsigned short lB[128 * 64];

    const int tid = threadIdx.x, w = tid >> 6, lane = tid & 63;
    const int lr = lane & 15, lg = lane >> 4;
    const int wm = (w >> 1) << 6, wn = (w & 1) << 6;

    const unsigned short* gA[4]; const unsigned short* gB[4]; int lo[4];
#pragma unroll
    for (int i = 0; i < 4; ++i) {
        const int q = (i * 4 + w) * 64 + lane, row = q >> 3, slot = q & 7;
        const int gs = (slot ^ (row & 7)) * 8;
        gA[i] = Ap + (long)(m0 + row) * S + gs;
        gB[i] = Bp + (long)(n0 + row) * S + gs;
        lo[i] = (i * 4 + w) * 512;
    }

    int abase[4], axor[4], bbase[4], bxor[4];
#pragma unroll
    for (int f = 0; f < 4; ++f) {
        const int ra = wm + f * 16 + lr;
        abase[f] = ra * 64; axor[f] = (ra & 7) * 8;
        const int rb = wn + f * 16 + lr;
        bbase[f] = rb * 64; bxor[f] = (rb & 7) * 8;
    }

    f32x4 acc[4][4] = {};

    for (int k0 = 0; k0 < S; k0 += 64) {
#pragma unroll
        for (int i = 0; i < 4; ++i) {
            gload16(gA[i] + k0, &lA[lo[i]]);
            gload16(gB[i] + k0, &lB[lo[i]]);
        }
        __syncthreads();
#pragma unroll
        for (int kk = 0; kk < 64; kk += 32) {
            s16x8 af[4], bv[4];
#pragma unroll
            for (int f = 0; f < 4; ++f) {
                af[f] = *reinterpret_cast<const s16x8*>(&lA[abase[f] + ((kk + 8 * lg) ^ axor[f])]);
                bv[f] = *reinterpret_cast<const s16x8*>(&lB[bbase[f] + ((kk + 8 * lg) ^ bxor[f])]);
            }
#pragma unroll
            for (int fm = 0; fm < 4; ++fm)
#pragma unroll
                for (int fn = 0; fn < 4; ++fn)
                    acc[fm][fn] = __builtin_amdgcn_mfma_f32_16x16x32_bf16(af[fm], bv[fn], acc[fm][fn], 0, 0, 0);
        }
        __syncthreads();
    }

    const long obase = (long)bz * SS;
#pragma unroll
    for (int fm = 0; fm < 4; ++fm) {
        const int t0 = m0 + wm + fm * 16 + lg * 4;
        float rec[4];
#pragma unroll
        for (int rr = 0; rr < 4; ++rr)
            rec[rr] = inv2[(long)bz * S + t0 + rr];
#pragma unroll
        for (int fn = 0; fn < 4; ++fn) {
            const int gn = n0 + wn + fn * 16 + lr;
#pragma unroll
            for (int rr = 0; rr < 4; ++rr) {
                const int gm = t0 + rr;
                const float vv = (gn <= gm) ? acc[fm][fn][rr] * rec[rr] : 0.f;
                Oall[obase + (long)gm * S + gn] = f2bf(vv);
            }
        }
    }
}

// ---------------------------------------------------------------------------
// gemmT: TMxTN-tile, BK=64, single-buffer m97 loop (round-7 verbatim) for the
// small GEMMs (projections, vhT, pack/sQK, attn_out, out-proj).
// ---------------------------------------------------------------------------
template<int TM, int TN, int EPI, bool CK, bool CS, bool SWZ, bool REVY>
__global__ __launch_bounds__((TM/64)*(TN/64)*64)
void gemmT(const unsigned short* __restrict__ Aall, long a_sb, long a_sh, int lda,
           const unsigned short* __restrict__ Ball, long b_sb, long b_sh, int ldb,
           void* __restrict__ Oall, void* __restrict__ O2, long o_sb, long o_sh, int ldo,
           const float* __restrict__ bias, int bstride, int K, int NV)
{
    constexpr int WN = TN / 64, WM = TM / 64, NWV = WM * WN, NTHR = NWV * 64;
    constexpr int IA = (TM * 8) / NTHR, IB = (TN * 8) / NTHR;

    int bx, by, bz;
    if (SWZ) {   // grid must be (8,8,32)
        const int L = (int)blockIdx.x + ((int)blockIdx.y << 3) + ((int)blockIdx.z << 6);
        const int g = L & 7, r = L >> 3;
        bz = g + ((r >> 6) << 3);
        bx = r & 7;
        by = 7 - ((r >> 3) & 7);                 // longest-K first
    } else {
        bx = blockIdx.x;
        by = REVY ? (int)gridDim.y - 1 - (int)blockIdx.y : (int)blockIdx.y;
        bz = blockIdx.z;
    }
    const int m0 = by * TM, n0 = bx * TN;
    if (CS && n0 > m0 + TM - 1) return;
    const int zb = bz >> 4, zh = bz & 15;
    const unsigned short* Ap = Aall + (long)zb * a_sb + (long)zh * a_sh;
    const unsigned short* Bp = Ball + (long)zb * b_sb + (long)zh * b_sh;
    const float* bi = bias + (long)zh * bstride;

    __shared__ alignas(16) unsigned short lA[TM * 64];
    __shared__ alignas(16) unsigned short lB[TN * 64];

    const int tid = threadIdx.x, w = tid >> 6, lane = tid & 63;
    const int lr = lane & 15, lg = lane >> 4;
    const int wm = (w / WN) * 64, wn = (w % WN) * 64;

    const unsigned short* gA[IA]; int loA[IA];
    const unsigned short* gB[IB]; int loB[IB];
#pragma unroll
    for (int i = 0; i < IA; ++i) {
        const int q = i * NTHR + tid, row = q >> 3, slot = q & 7;
        gA[i]  = Ap + (long)(m0 + row) * lda + ((slot ^ (row & 7)) * 8);
        loA[i] = (i * NWV + w) * 512;
    }
#pragma unroll
    for (int i = 0; i < IB; ++i) {
        const int q = i * NTHR + tid, row = q >> 3, slot = q & 7;
        int rb = n0 + row; if (rb >= NV) rb = NV - 1;
        gB[i]  = Bp + (long)rb * ldb + ((slot ^ (row & 7)) * 8);
        loB[i] = (i * NWV + w) * 512;
    }

    int abase[4], axor[4], bbase[4], bxor[4];
#pragma unroll
    for (int f = 0; f < 4; ++f) {
        const int ra = wm + f * 16 + lr;
        abase[f] = ra * 64; axor[f] = (ra & 7) * 8;
        const int rb = wn + f * 16 + lr;
        bbase[f] = rb * 64; bxor[f] = (rb & 7) * 8;
    }

    f32x4 acc[4][4] = {};
    const int Keff = CK ? ((K < m0 + TM) ? K : m0 + TM) : K;

    for (int k0 = 0; k0 < Keff; k0 += 64) {
#pragma unroll
        for (int i = 0; i < IA; ++i) gload16(gA[i] + k0, &lA[loA[i]]);
#pragma unroll
        for (int i = 0; i < IB; ++i) gload16(gB[i] + k0, &lB[loB[i]]);
        __syncthreads();
#pragma unroll
        for (int kk = 0; kk < 64; kk += 32) {
            s16x8 af[4], bv[4];
#pragma unroll
            for (int f = 0; f < 4; ++f) {
                af[f] = *reinterpret_cast<const s16x8*>(&lA[abase[f] + ((kk + 8 * lg) ^ axor[f])]);
                bv[f] = *reinterpret_cast<const s16x8*>(&lB[bbase[f] + ((kk + 8 * lg) ^ bxor[f])]);
            }
#pragma unroll
            for (int fm = 0; fm < 4; ++fm)
#pragma unroll
                for (int fn = 0; fn < 4; ++fn)
                    acc[fm][fn] = __builtin_amdgcn_mfma_f32_16x16x32_bf16(af[fm], bv[fn], acc[fm][fn], 0, 0, 0);
        }
        __syncthreads();
    }

    const long obase = (long)zb * o_sb + (long)zh * o_sh;
#pragma unroll
    for (int fm = 0; fm < 4; ++fm)
#pragma unroll
        for (int fn = 0; fn < 4; ++fn) {
            const int t0 = m0 + wm + fm * 16 + lg * 4;
            const int gn = n0 + wn + fn * 16 + lr;
            if (gn >= NV) continue;
            if constexpr (EPI == EPI_PACK2) {             // dual store: P and P^T
                ushort4 pt;
                unsigned short* o1 = (unsigned short*)Oall;
                unsigned short* o2 = (unsigned short*)O2;
#pragma unroll
                for (int r = 0; r < 4; ++r) {
                    float vv = acc[fm][fn][r];
                    vv = vv > 0.f ? vv + 1.f : __expf(vv);   // elu(x)+1
                    const unsigned short b = f2bf(vv);
                    o1[obase + (long)(t0 + r) * ldo + gn] = b;
                    ((unsigned short*)&pt)[r] = b;
                }
                *reinterpret_cast<ushort4*>(&o2[obase + (long)gn * ldo + t0]) = pt;
            } else {
#pragma unroll
                for (int r = 0; r < 4; ++r) {
                    const int gm = t0 + r;
                    float vv = acc[fm][fn][r];
                    const long o = obase + (long)gm * ldo + gn;
                    if constexpr (EPI == EPI_BFB) {
                        ((unsigned short*)Oall)[o] = f2bf(vv + bi[gn]);
                    } else if constexpr (EPI == EPI_VTB) {
                        ((unsigned short*)Oall)[o] = f2bf(vv + bi[gm]);
                    } else if constexpr (EPI == EPI_PACK) {
                        vv = vv > 0.f ? vv + 1.f : __expf(vv);
                        ((unsigned short*)Oall)[o] = f2bf(vv);
                    } else if constexpr (EPI == EPI_MASK) {
                        vv = (gn <= gm) ? vv / (float)(gm + 1) : 0.f;
                        ((unsigned short*)Oall)[o] = f2bf(vv);
                    } else if constexpr (EPI == EPI_BF) {
                        ((unsigned short*)Oall)[o] = f2bf(vv);
                    } else { // EPI_OUT
                        ((float*)Oall)[o] = vv + bi[gn];
                    }
                }
            }
        }
}

// wave-per-row: inv2[row] = 1 / (rowsum(E) * (t+1)), t = row mod S
__global__ __launch_bounds__(256)
void rowsum_inv(const unsigned short* __restrict__ E, float* __restrict__ inv2)
{
    const int w = threadIdx.x >> 6, lane = threadIdx.x & 63;
    const long row = (long)blockIdx.x * 4 + w;
    const u32x4* r4 = reinterpret_cast<const u32x4*>(E + row * S);
    u32x4 a = r4[lane * 2], b = r4[lane * 2 + 1];
    float s = 0.f;
#pragma unroll
    for (int i = 0; i < 4; ++i) {
        s += bf2f((unsigned short)(a[i] & 0xFFFF)) + bf2f((unsigned short)(a[i] >> 16));
        s += bf2f((unsigned short)(b[i] & 0xFFFF)) + bf2f((unsigned short)(b[i] >> 16));
    }
#pragma unroll
    for (int off = 32; off; off >>= 1) s += __shfl_xor(s, off);
    if (lane == 0) inv2[row] = 1.f / (s * (float)((row & (S - 1)) + 1));
}

// z selects one of 4 sources; dst contiguous per z
__global__ __launch_bounds__(256)
void cast4(const float* __restrict__ s0, const float* __restrict__ s1,
           const float* __restrict__ s2, const float* __restrict__ s3,
           unsigned short* __restrict__ dst, int n4)
{
    const int i = blockIdx.x * 256 + threadIdx.x;
    if (i >= n4) return;
    const float* s = (blockIdx.z == 0) ? s0 : (blockIdx.z == 1) ? s1 : (blockIdx.z == 2) ? s2 : s3;
    float4 x = reinterpret_cast<const float4*>(s)[i];
    ushort4 o; o.x = f2bf(x.x); o.y = f2bf(x.y); o.z = f2bf(x.z); o.w = f2bf(x.w);
    reinterpret_cast<ushort4*>(dst + (size_t)blockIdx.z * n4 * 4)[i] = o;
}

// f32 [n][n] -> bf16 transposed [n][n], scaled; z selects src, dst contiguous
__global__ __launch_bounds__(256)
void twcast4(const float* __restrict__ s0, const float* __restrict__ s1,
             const float* __restrict__ s2, const float* __restrict__ s3,
             unsigned short* __restrict__ dstall, int n)
{
    __shared__ unsigned short t[64][72];
    const float* src = (blockIdx.z == 0) ? s0 : (blockIdx.z == 1) ? s1 : (blockIdx.z == 2) ? s2 : s3;
    const float scale = (blockIdx.z == 0) ? 0.125f : 1.0f;
    unsigned short* dst = dstall + (size_t)blockIdx.z * n * n;
    const int r0 = blockIdx.y * 64, c0 = blockIdx.x * 64;
    const int lrow = threadIdx.x >> 2, lseg = (threadIdx.x & 3) << 4;
    const float4* g4 = reinterpret_cast<const float4*>(src + (long)(r0 + lrow) * n + c0 + lseg);
    alignas(16) unsigned short tmp[16];
#pragma unroll
    for (int q = 0; q < 4; ++q) {
        float4 x = g4[q];
        tmp[4*q+0] = f2bf(x.x * scale); tmp[4*q+1] = f2bf(x.y * scale);
        tmp[4*q+2] = f2bf(x.z * scale); tmp[4*q+3] = f2bf(x.w * scale);
    }
#pragma unroll
    for (int j = 0; j < 16; ++j) t[lrow][lseg + j] = tmp[j];
    __syncthreads();
#pragma unroll
    for (int j = 0; j < 16; ++j) tmp[j] = t[lseg + j][lrow];
    unsigned short* d = dst + (long)(c0 + lrow) * n + r0 + lseg;
    *reinterpret_cast<u32x4*>(d)     = *reinterpret_cast<const u32x4*>(tmp);
    *reinterpret_cast<u32x4*>(d + 8) = *reinterpret_cast<const u32x4*>(tmp + 8);
}

// bq2[0][:] = wqb * 0.125, bq2[1][:] = wkb
__global__ __launch_bounds__(256)
void bias2(const float* __restrict__ a, const float* __restrict__ b, float* __restrict__ dst)
{
    const int i = blockIdx.x * 256 + threadIdx.x;
    if (i < DM) { dst[i] = a[i] * 0.125f; dst[DM + i] = b[i]; }
}

extern "C" void kernel_launch(void* const* d_in, const int* in_sizes, int n_in,
                              void* d_out, int out_size, void* d_ws, size_t ws_size,
                              hipStream_t stream)
{
    (void)in_sizes; (void)n_in; (void)out_size;
    const float* v_in = (const float*)d_in[0];
    const float* k_in = (const float*)d_in[1];
    const float* q_in = (const float*)d_in[2];
    const float* p_in = (const float*)d_in[3];
    const float* wq   = (const float*)d_in[4];
    const float* wqb  = (const float*)d_in[5];
    const float* wk   = (const float*)d_in[6];
    const float* wkb  = (const float*)d_in[7];
    const float* wvw  = (const float*)d_in[8];
    const float* wvb  = (const float*)d_in[9];
    const float* wc   = (const float*)d_in[10];
    const float* wcb  = (const float*)d_in[11];
    float* out = (float*)d_out;

    char* ws = (char*)d_ws;
    size_t off = 0;
    auto take = [&](size_t n) { char* p = ws + off; off += (n + 255) & ~(size_t)255; return p; };
    unsigned short* qbf = (unsigned short*)take((size_t)BS * DM * 2);  // qbf..pbf contiguous
    unsigned short* kbf = (unsigned short*)take((size_t)BS * DM * 2);
    unsigned short* vbf = (unsigned short*)take((size_t)BS * DM * 2);
    unsigned short* pbf = (unsigned short*)take((size_t)BS * DM * 2);
    unsigned short* wqT = (unsigned short*)take((size_t)DM * DM * 2);  // wqT..wcT contiguous
    unsigned short* wkT = (unsigned short*)take((size_t)DM * DM * 2);
    unsigned short* wvT = (unsigned short*)take((size_t)DM * DM * 2);
    unsigned short* wcT = (unsigned short*)take((size_t)DM * DM * 2);
    float*          bq2 = (float*)take((size_t)2 * DM * 4);
    float*          inv = (float*)take((size_t)NB * H * S * 4);
    unsigned short* qh  = (unsigned short*)take((size_t)BS * DM * 2);  // qh,kh contiguous
    unsigned short* kh  = (unsigned short*)take((size_t)BS * DM * 2);
    unsigned short* vhT = (unsigned short*)take((size_t)BS * DM * 2);
    unsigned short* ao  = (unsigned short*)take((size_t)BS * DM * 2);
    const size_t ssz = (size_t)NB * HSS * 2;
    unsigned short* B1 = (unsigned short*)take(ssz);
    unsigned short* B2 = (unsigned short*)take(ssz);
    unsigned short* B3 = (unsigned short*)take(ssz);
    const bool dual = (ws_size >= off + ssz);          // 4th S x S buffer fits?
    unsigned short* B4 = dual ? (unsigned short*)take(ssz) : nullptr;
    (void)kbf; (void)wkT;

    const int n4 = BS * DM / 4;
    const dim3 b256(256), b128(128);

    cast4<<<dim3(n4 / 256, 1, 4), b256, 0, stream>>>(q_in, k_in, v_in, p_in, qbf, n4);
    twcast4<<<dim3(16, 16, 4), b256, 0, stream>>>(wq, wk, wvw, wc, wqT, DM);
    bias2<<<dim3(4), b256, 0, stream>>>(wqb, wkb, bq2);

    // q,k projections merged over z (alpha folded into wqT/bq2), 64x128 tiles
    gemmT<64,128,EPI_BFB,false,false,false,false><<<dim3(8, 32, 2), b128, 0, stream>>>(
        qbf, 0, (long)BS*DM, DM,  wqT, 0, (long)DM*DM, DM,  qh, nullptr, 0, (long)BS*DM, DM,
        bq2, DM, DM, DM);
    // vhT[b][dm][t] = (v@wv + b)^T, 64x128 tiles
    gemmT<64,128,EPI_VTB,false,false,false,false><<<dim3(8, 16, 2), b128, 0, stream>>>(
        wvT, 0, 0, DM,  vbf, 0, SDM, DM,  vhT, nullptr, 0, (long)DM*S, S,
        wvb, 0, DM, S);

    unsigned short *pbuf, *ptbuf, *sqkbuf, *ebuf, *s2buf;
    if (dual) {
        // P -> B1, P^T -> B2 in one pass
        gemmT<128,128,EPI_PACK2,false,false,true,false><<<dim3(8, 8, 32), b256, 0, stream>>>(
            qh, SDM, 64, DM,  pbf, SDM, 64, DM,  B1, B2, HSS, SS, S,  wvb, 0, 64, S);
        pbuf = B1; ptbuf = B2; sqkbuf = B3; ebuf = B4; s2buf = B3;
    } else {
        // packT[s][t] = elu(ph[s].qh[t])+1 -> B1
        gemmT<128,128,EPI_PACK,false,false,true,false><<<dim3(8, 8, 32), b256, 0, stream>>>(
            pbf, SDM, 64, DM,  qh, SDM, 64, DM,  B1, nullptr, HSS, SS, S,  wvb, 0, 64, S);
        ptbuf = B1; sqkbuf = B2; ebuf = B3; pbuf = B1; s2buf = B2;
    }
    // sQK[t][s] = (qh.kh) * tril/(t+1)
    gemmT<128,128,EPI_MASK,false,true,true,false><<<dim3(8, 8, 32), b256, 0, stream>>>(
        qh, SDM, 64, DM,  kh, SDM, 64, DM,  sqkbuf, nullptr, HSS, SS, S,  wvb, 0, 64, S);
    // E = exp(sQK @ P) (B = P^T rows j), causal-K -> ebuf (bf16, unnormalized)
    gemmU<<<dim3(8, 8, 32), b256, 0, stream>>>(sqkbuf, ptbuf, ebuf);
    // inv2[row] = 1 / (rowsum(E) * (t+1))
    rowsum_inv<<<dim3(NB*H*S/4), b256, 0, stream>>>(ebuf, inv);
    if (!dual) {
        // pack[t][s] = elu(qh.ph)+1 -> B1 (packT dead)
        gemmT<128,128,EPI_PACK,false,false,true,false><<<dim3(8, 8, 32), b256, 0, stream>>>(
            qh, SDM, 64, DM,  pbf, SDM, 64, DM,  B1, nullptr, HSS, SS, S,  wvb, 0, 64, S);
    }
    // s2[t][s] = (E[t,:].P[s,:]) * inv2[t], causal-skip -> s2buf (sQK dead)
    gemmV<<<dim3(8, 8, 32), b256, 0, stream>>>(ebuf, pbuf, s2buf, inv);
    // attn_out[t][d] = s2 @ vh (B = vhT head-slice [d][s]), 128x64 tiles, causal-K
    gemmT<128,64,EPI_BF,true,false,false,true><<<dim3(1, 8, 32), b128, 0, stream>>>(
        s2buf, HSS, SS, S,  vhT, (long)DM*S, (long)64*S, S,  ao, nullptr, SDM, 64, DM,
        wvb, 0, S, 64);
    // out = ao @ wc + b (f32), 64x128 tiles
    gemmT<64,128,EPI_OUT,false,false,false,false><<<dim3(8, 32, 1), b128, 0, stream>>>(
        ao, 0, 0, DM,  wcT, 0, 0, DM,  out, nullptr, 0, 0, DM,  wcb, 0, DM, DM);
}

// Round 12
// 294.986 us; speedup vs baseline: 1.0830x; 1.0125x over previous
//
#include <hip/hip_runtime.h>

#define DEVI static __device__ __forceinline__

using s16x8 = __attribute__((ext_vector_type(8))) short;
using f32x4 = __attribute__((ext_vector_type(4))) float;
using u32x4 = __attribute__((ext_vector_type(4))) unsigned int;

static constexpr int H  = 16;
static constexpr int S  = 1024;
static constexpr int DM = 1024;
static constexpr int NB = 2;          // batch
static constexpr int BS = NB * S;     // 2048
static constexpr long SS  = (long)S * S;
static constexpr long HSS = (long)H * SS;
static constexpr long SDM = (long)S * DM;

DEVI unsigned short f2bf(float f) {
    union { float f; unsigned u; } c; c.f = f;
    c.u += 0x7FFFu + ((c.u >> 16) & 1u);   // RNE
    return (unsigned short)(c.u >> 16);
}
DEVI float bf2f(unsigned short v) {
    union { unsigned u; float f; } c; c.u = ((unsigned)v) << 16;
    return c.f;
}

// async global->LDS, 16 bytes per lane; lds dest = wave-uniform base + lane*16
DEVI void gload16(const unsigned short* g, unsigned short* l) {
    __builtin_amdgcn_global_load_lds(
        (const __attribute__((address_space(1))) unsigned int*)g,
        (__attribute__((address_space(3))) unsigned int*)l, 16, 0, 0);
}

enum { EPI_BFB = 0, EPI_VTB, EPI_PACK, EPI_PACK2, EPI_MASK, EPI_BF, EPI_OUT };

// ---------------------------------------------------------------------------
// gemmU: dedicated unpack kernel (plain function, r11 VERBATIM — 63.5us).
// E = exp(sQK @ P^T-rows), causal-K capped. Grid (8,8,32).
// ---------------------------------------------------------------------------
__global__ __launch_bounds__(256)
void gemmU(const unsigned short* __restrict__ Aall,
           const unsigned short* __restrict__ Ball,
           unsigned short* __restrict__ Oall)
{
    const int L = (int)blockIdx.x + ((int)blockIdx.y << 3) + ((int)blockIdx.z << 6);
    const int g = L & 7, r = L >> 3;
    const int bz = g + ((r >> 6) << 3);
    const int bx = r & 7;
    const int by = 7 - ((r >> 3) & 7);           // longest-K first
    const int m0 = by * 128, n0 = bx * 128;
    const unsigned short* Ap = Aall + (long)bz * SS;
    const unsigned short* Bp = Ball + (long)bz * SS;

    __shared__ alignas(16) unsigned short lA[128 * 64];
    __shared__ alignas(16) unsigned short lB[128 * 64];

    const int tid = threadIdx.x, w = tid >> 6, lane = tid & 63;
    const int lr = lane & 15, lg = lane >> 4;
    const int wm = (w >> 1) << 6, wn = (w & 1) << 6;

    const unsigned short* gA[4]; const unsigned short* gB[4]; int lo[4];
#pragma unroll
    for (int i = 0; i < 4; ++i) {
        const int q = (i * 4 + w) * 64 + lane, row = q >> 3, slot = q & 7;
        const int gs = (slot ^ (row & 7)) * 8;
        gA[i] = Ap + (long)(m0 + row) * S + gs;
        gB[i] = Bp + (long)(n0 + row) * S + gs;
        lo[i] = (i * 4 + w) * 512;
    }

    int abase[4], axor[4], bbase[4], bxor[4];
#pragma unroll
    for (int f = 0; f < 4; ++f) {
        const int ra = wm + f * 16 + lr;
        abase[f] = ra * 64; axor[f] = (ra & 7) * 8;
        const int rb = wn + f * 16 + lr;
        bbase[f] = rb * 64; bxor[f] = (rb & 7) * 8;
    }

    f32x4 acc[4][4] = {};
    const int Keff = m0 + 128;                   // causal-K cap

    for (int k0 = 0; k0 < Keff; k0 += 64) {
#pragma unroll
        for (int i = 0; i < 4; ++i) {
            gload16(gA[i] + k0, &lA[lo[i]]);
            gload16(gB[i] + k0, &lB[lo[i]]);
        }
        __syncthreads();
#pragma unroll
        for (int kk = 0; kk < 64; kk += 32) {
            s16x8 af[4], bv[4];
#pragma unroll
            for (int f = 0; f < 4; ++f) {
                af[f] = *reinterpret_cast<const s16x8*>(&lA[abase[f] + ((kk + 8 * lg) ^ axor[f])]);
                bv[f] = *reinterpret_cast<const s16x8*>(&lB[bbase[f] + ((kk + 8 * lg) ^ bxor[f])]);
            }
#pragma unroll
            for (int fm = 0; fm < 4; ++fm)
#pragma unroll
                for (int fn = 0; fn < 4; ++fn)
                    acc[fm][fn] = __builtin_amdgcn_mfma_f32_16x16x32_bf16(af[fm], bv[fn], acc[fm][fn], 0, 0, 0);
        }
        __syncthreads();
    }

    const long obase = (long)bz * SS;
#pragma unroll
    for (int fm = 0; fm < 4; ++fm)
#pragma unroll
        for (int fn = 0; fn < 4; ++fn) {
            const int t0 = m0 + wm + fm * 16 + lg * 4;
            const int gn = n0 + wn + fn * 16 + lr;
#pragma unroll
            for (int rr = 0; rr < 4; ++rr)
                Oall[obase + (long)(t0 + rr) * S + gn] = f2bf(__expf(acc[fm][fn][rr]));
        }
}

// ---------------------------------------------------------------------------
// gemmV: dedicated s2 kernel (plain function, r11 VERBATIM — 63.5us).
// s2 = (E.P) * inv2[t], masked; inv2[t] = 1/(rowsum(E)*(t+1)). Grid (8,8,32).
// ---------------------------------------------------------------------------
__global__ __launch_bounds__(256)
void gemmV(const unsigned short* __restrict__ Aall,
           const unsigned short* __restrict__ Ball,
           unsigned short* __restrict__ Oall, const float* __restrict__ inv2)
{
    const int L = (int)blockIdx.x + ((int)blockIdx.y << 3) + ((int)blockIdx.z << 6);
    const int g = L & 7, r = L >> 3;
    const int bz = g + ((r >> 6) << 3);
    const int bx = r & 7;
    const int by = 7 - ((r >> 3) & 7);
    const int m0 = by * 128, n0 = bx * 128;
    if (n0 > m0 + 127) return;
    const unsigned short* Ap = Aall + (long)bz * SS;
    const unsigned short* Bp = Ball + (long)bz * SS;

    __shared__ alignas(16) unsigned short lA[128 * 64];
    __shared__ alignas(16) unsigned short lB[128 * 64];

    const int tid = threadIdx.x, w = tid >> 6, lane = tid & 63;
    const int lr = lane & 15, lg = lane >> 4;
    const int wm = (w >> 1) << 6, wn = (w & 1) << 6;

    const unsigned short* gA[4]; const unsigned short* gB[4]; int lo[4];
#pragma unroll
    for (int i = 0; i < 4; ++i) {
        const int q = (i * 4 + w) * 64 + lane, row = q >> 3, slot = q & 7;
        const int gs = (slot ^ (row & 7)) * 8;
        gA[i] = Ap + (long)(m0 + row) * S + gs;
        gB[i] = Bp + (long)(n0 + row) * S + gs;
        lo[i] = (i * 4 + w) * 512;
    }

    int abase[4], axor[4], bbase[4], bxor[4];
#pragma unroll
    for (int f = 0; f < 4; ++f) {
        const int ra = wm + f * 16 + lr;
        abase[f] = ra * 64; axor[f] = (ra & 7) * 8;
        const int rb = wn + f * 16 + lr;
        bbase[f] = rb * 64; bxor[f] = (rb & 7) * 8;
    }

    f32x4 acc[4][4] = {};

    for (int k0 = 0; k0 < S; k0 += 64) {
#pragma unroll
        for (int i = 0; i < 4; ++i) {
            gload16(gA[i] + k0, &lA[lo[i]]);
            gload16(gB[i] + k0, &lB[lo[i]]);
        }
        __syncthreads();
#pragma unroll
        for (int kk = 0; kk < 64; kk += 32) {
            s16x8 af[4], bv[4];
#pragma unroll
            for (int f = 0; f < 4; ++f) {
                af[f] = *reinterpret_cast<const s16x8*>(&lA[abase[f] + ((kk + 8 * lg) ^ axor[f])]);
                bv[f] = *reinterpret_cast<const s16x8*>(&lB[bbase[f] + ((kk + 8 * lg) ^ bxor[f])]);
            }
#pragma unroll
            for (int fm = 0; fm < 4; ++fm)
#pragma unroll
                for (int fn = 0; fn < 4; ++fn)
                    acc[fm][fn] = __builtin_amdgcn_mfma_f32_16x16x32_bf16(af[fm], bv[fn], acc[fm][fn], 0, 0, 0);
        }
        __syncthreads();
    }

    const long obase = (long)bz * SS;
#pragma unroll
    for (int fm = 0; fm < 4; ++fm) {
        const int t0 = m0 + wm + fm * 16 + lg * 4;
        float rec[4];
#pragma unroll
        for (int rr = 0; rr < 4; ++rr)
            rec[rr] = inv2[(long)bz * S + t0 + rr];
#pragma unroll
        for (int fn = 0; fn < 4; ++fn) {
            const int gn = n0 + wn + fn * 16 + lr;
#pragma unroll
            for (int rr = 0; rr < 4; ++rr) {
                const int gm = t0 + rr;
                const float vv = (gn <= gm) ? acc[fm][fn][rr] * rec[rr] : 0.f;
                Oall[obase + (long)gm * S + gn] = f2bf(vv);
            }
        }
    }
}

// ---------------------------------------------------------------------------
// gemmT: TMxTN-tile m97 loop for the small GEMMs (proj, vhT, attn_out, out,
// plus non-dual PACK/MASK fallback)
// ---------------------------------------------------------------------------
template<int TM, int TN, int EPI, bool CK, bool CS, bool SWZ, bool REVY>
__global__ __launch_bounds__((TM/64)*(TN/64)*64)
void gemmT(const unsigned short* __restrict__ Aall, long a_sb, long a_sh, int lda,
           const unsigned short* __restrict__ Ball, long b_sb, long b_sh, int ldb,
           void* __restrict__ Oall, void* __restrict__ O2, long o_sb, long o_sh, int ldo,
           const float* __restrict__ bias, int bstride, int K, int NV)
{
    constexpr int WN = TN / 64, WM = TM / 64, NWV = WM * WN, NTHR = NWV * 64;
    constexpr int IA = (TM * 8) / NTHR, IB = (TN * 8) / NTHR;

    int bx, by, bz;
    if (SWZ) {   // grid must be (8,8,32)
        const int L = (int)blockIdx.x + ((int)blockIdx.y << 3) + ((int)blockIdx.z << 6);
        const int g = L & 7, r = L >> 3;
        bz = g + ((r >> 6) << 3);
        bx = r & 7;
        by = 7 - ((r >> 3) & 7);                 // longest-K first
    } else {
        bx = blockIdx.x;
        by = REVY ? (int)gridDim.y - 1 - (int)blockIdx.y : (int)blockIdx.y;
        bz = blockIdx.z;
    }
    const int m0 = by * TM, n0 = bx * TN;
    if (CS && n0 > m0 + TM - 1) return;
    const int zb = bz >> 4, zh = bz & 15;
    const unsigned short* Ap = Aall + (long)zb * a_sb + (long)zh * a_sh;
    const unsigned short* Bp = Ball + (long)zb * b_sb + (long)zh * b_sh;
    const float* bi = bias + (long)zh * bstride;

    __shared__ alignas(16) unsigned short lA[TM * 64];
    __shared__ alignas(16) unsigned short lB[TN * 64];

    const int tid = threadIdx.x, w = tid >> 6, lane = tid & 63;
    const int lr = lane & 15, lg = lane >> 4;
    const int wm = (w / WN) * 64, wn = (w % WN) * 64;

    const unsigned short* gA[IA]; int loA[IA];
    const unsigned short* gB[IB]; int loB[IB];
#pragma unroll
    for (int i = 0; i < IA; ++i) {
        const int q = i * NTHR + tid, row = q >> 3, slot = q & 7;
        gA[i]  = Ap + (long)(m0 + row) * lda + ((slot ^ (row & 7)) * 8);
        loA[i] = (i * NWV + w) * 512;
    }
#pragma unroll
    for (int i = 0; i < IB; ++i) {
        const int q = i * NTHR + tid, row = q >> 3, slot = q & 7;
        int rb = n0 + row; if (rb >= NV) rb = NV - 1;
        gB[i]  = Bp + (long)rb * ldb + ((slot ^ (row & 7)) * 8);
        loB[i] = (i * NWV + w) * 512;
    }

    int abase[4], axor[4], bbase[4], bxor[4];
#pragma unroll
    for (int f = 0; f < 4; ++f) {
        const int ra = wm + f * 16 + lr;
        abase[f] = ra * 64; axor[f] = (ra & 7) * 8;
        const int rb = wn + f * 16 + lr;
        bbase[f] = rb * 64; bxor[f] = (rb & 7) * 8;
    }

    f32x4 acc[4][4] = {};
    const int Keff = CK ? ((K < m0 + TM) ? K : m0 + TM) : K;

    for (int k0 = 0; k0 < Keff; k0 += 64) {
#pragma unroll
        for (int i = 0; i < IA; ++i) gload16(gA[i] + k0, &lA[loA[i]]);
#pragma unroll
        for (int i = 0; i < IB; ++i) gload16(gB[i] + k0, &lB[loB[i]]);
        __syncthreads();
#pragma unroll
        for (int kk = 0; kk < 64; kk += 32) {
            s16x8 af[4], bv[4];
#pragma unroll
            for (int f = 0; f < 4; ++f) {
                af[f] = *reinterpret_cast<const s16x8*>(&lA[abase[f] + ((kk + 8 * lg) ^ axor[f])]);
                bv[f] = *reinterpret_cast<const s16x8*>(&lB[bbase[f] + ((kk + 8 * lg) ^ bxor[f])]);
            }
#pragma unroll
            for (int fm = 0; fm < 4; ++fm)
#pragma unroll
                for (int fn = 0; fn < 4; ++fn)
                    acc[fm][fn] = __builtin_amdgcn_mfma_f32_16x16x32_bf16(af[fm], bv[fn], acc[fm][fn], 0, 0, 0);
        }
        __syncthreads();
    }

    const long obase = (long)zb * o_sb + (long)zh * o_sh;
#pragma unroll
    for (int fm = 0; fm < 4; ++fm)
#pragma unroll
        for (int fn = 0; fn < 4; ++fn) {
            const int t0 = m0 + wm + fm * 16 + lg * 4;
            const int gn = n0 + wn + fn * 16 + lr;
            if (gn >= NV) continue;
            if constexpr (EPI == EPI_PACK2) {             // dual store: P and P^T
                ushort4 pt;
                unsigned short* o1 = (unsigned short*)Oall;
                unsigned short* o2 = (unsigned short*)O2;
#pragma unroll
                for (int r = 0; r < 4; ++r) {
                    float vv = acc[fm][fn][r];
                    vv = vv > 0.f ? vv + 1.f : __expf(vv);   // elu(x)+1
                    const unsigned short b = f2bf(vv);
                    o1[obase + (long)(t0 + r) * ldo + gn] = b;
                    ((unsigned short*)&pt)[r] = b;
                }
                *reinterpret_cast<ushort4*>(&o2[obase + (long)gn * ldo + t0]) = pt;
            } else {
#pragma unroll
                for (int r = 0; r < 4; ++r) {
                    const int gm = t0 + r;
                    float vv = acc[fm][fn][r];
                    const long o = obase + (long)gm * ldo + gn;
                    if constexpr (EPI == EPI_BFB) {
                        ((unsigned short*)Oall)[o] = f2bf(vv + bi[gn]);
                    } else if constexpr (EPI == EPI_VTB) {
                        ((unsigned short*)Oall)[o] = f2bf(vv + bi[gm]);
                    } else if constexpr (EPI == EPI_PACK) {
                        vv = vv > 0.f ? vv + 1.f : __expf(vv);
                        ((unsigned short*)Oall)[o] = f2bf(vv);
                    } else if constexpr (EPI == EPI_MASK) {
                        vv = (gn <= gm) ? vv / (float)(gm + 1) : 0.f;
                        ((unsigned short*)Oall)[o] = f2bf(vv);
                    } else if constexpr (EPI == EPI_BF) {
                        ((unsigned short*)Oall)[o] = f2bf(vv);
                    } else { // EPI_OUT
                        ((float*)Oall)[o] = vv + bi[gn];
                    }
                }
            }
        }
}

// ---------------------------------------------------------------------------
// packsqk: merged pack2 + sQK (both 128x128-tile, K=64). Grid (8,8,64):
// z-swizzled; job = high bit (0: P/P^T dual store, 1: masked QK^T causal-skip)
// ---------------------------------------------------------------------------
__global__ __launch_bounds__(256)
void packsqk(const unsigned short* __restrict__ qh,
             const unsigned short* __restrict__ pbf,
             const unsigned short* __restrict__ kh,
             unsigned short* __restrict__ P, unsigned short* __restrict__ PT,
             unsigned short* __restrict__ SQ)
{
    const int L = (int)blockIdx.x + ((int)blockIdx.y << 3) + ((int)blockIdx.z << 6);
    const int g = L & 7, r = L >> 3;
    const int bzz = g + ((r >> 6) << 3);          // 0..63
    const int bx = r & 7, by = 7 - ((r >> 3) & 7);
    const int job = bzz >> 5, zz = bzz & 31;
    const int m0 = by * 128, n0 = bx * 128;
    if (job && n0 > m0 + 127) return;
    const int zb = zz >> 4, zh = zz & 15;
    const unsigned short* Ap = qh + (long)zb * SDM + zh * 64;
    const unsigned short* Bp = (job ? kh : pbf) + (long)zb * SDM + zh * 64;

    __shared__ alignas(16) unsigned short lA[128 * 64];
    __shared__ alignas(16) unsigned short lB[128 * 64];

    const int tid = threadIdx.x, w = tid >> 6, lane = tid & 63;
    const int lr = lane & 15, lg = lane >> 4;
    const int wm = (w >> 1) << 6, wn = (w & 1) << 6;

#pragma unroll
    for (int i = 0; i < 4; ++i) {
        const int q = i * 256 + tid, row = q >> 3, slot = q & 7;
        const int gs = (slot ^ (row & 7)) * 8;
        gload16(Ap + (long)(m0 + row) * DM + gs, &lA[(i * 4 + w) * 512]);
        gload16(Bp + (long)(n0 + row) * DM + gs, &lB[(i * 4 + w) * 512]);
    }
    __syncthreads();

    f32x4 acc[4][4] = {};
#pragma unroll
    for (int kk = 0; kk < 64; kk += 32) {
        s16x8 af[4], bv[4];
#pragma unroll
        for (int f = 0; f < 4; ++f) {
            const int ra = wm + f * 16 + lr;
            af[f] = *reinterpret_cast<const s16x8*>(&lA[ra * 64 + ((kk + 8 * lg) ^ ((ra & 7) * 8))]);
            const int rb = wn + f * 16 + lr;
            bv[f] = *reinterpret_cast<const s16x8*>(&lB[rb * 64 + ((kk + 8 * lg) ^ ((rb & 7) * 8))]);
        }
#pragma unroll
        for (int fm = 0; fm < 4; ++fm)
#pragma unroll
            for (int fn = 0; fn < 4; ++fn)
                acc[fm][fn] = __builtin_amdgcn_mfma_f32_16x16x32_bf16(af[fm], bv[fn], acc[fm][fn], 0, 0, 0);
    }

    const long obase = (long)zz * SS;
#pragma unroll
    for (int fm = 0; fm < 4; ++fm)
#pragma unroll
        for (int fn = 0; fn < 4; ++fn) {
            const int t0 = m0 + wm + fm * 16 + lg * 4;
            const int gn = n0 + wn + fn * 16 + lr;
            if (job == 0) {                        // P and P^T dual store
                ushort4 pt;
#pragma unroll
                for (int rr = 0; rr < 4; ++rr) {
                    float vv = acc[fm][fn][rr];
                    vv = vv > 0.f ? vv + 1.f : __expf(vv);
                    const unsigned short b = f2bf(vv);
                    P[obase + (long)(t0 + rr) * S + gn] = b;
                    ((unsigned short*)&pt)[rr] = b;
                }
                *reinterpret_cast<ushort4*>(&PT[obase + (long)gn * S + t0]) = pt;
            } else {                               // masked QK^T
#pragma unroll
                for (int rr = 0; rr < 4; ++rr) {
                    const int gm = t0 + rr;
                    float vv = acc[fm][fn][rr];
                    vv = (gn <= gm) ? vv / (float)(gm + 1) : 0.f;
                    SQ[obase + (long)gm * S + gn] = f2bf(vv);
                }
            }
        }
}

// wave-per-row: inv2[row] = 1 / (rowsum(E) * (t+1)), t = row mod S
__global__ __launch_bounds__(256)
void rowsum_inv(const unsigned short* __restrict__ E, float* __restrict__ inv2)
{
    const int w = threadIdx.x >> 6, lane = threadIdx.x & 63;
    const long row = (long)blockIdx.x * 4 + w;
    const u32x4* r4 = reinterpret_cast<const u32x4*>(E + row * S);
    u32x4 a = r4[lane * 2], b = r4[lane * 2 + 1];
    float s = 0.f;
#pragma unroll
    for (int i = 0; i < 4; ++i) {
        s += bf2f((unsigned short)(a[i] & 0xFFFF)) + bf2f((unsigned short)(a[i] >> 16));
        s += bf2f((unsigned short)(b[i] & 0xFFFF)) + bf2f((unsigned short)(b[i] >> 16));
    }
#pragma unroll
    for (int off = 32; off; off >>= 1) s += __shfl_xor(s, off);
    if (lane == 0) inv2[row] = 1.f / (s * (float)((row & (S - 1)) + 1));
}

// ---------------------------------------------------------------------------
// prep: merged input casts (z=0..3), weight transposes (z=4..7), bias pack (z=8)
// grid (2048, 1, 9) x 256 threads
// ---------------------------------------------------------------------------
__global__ __launch_bounds__(256)
void prep(const float* __restrict__ q_in, const float* __restrict__ k_in,
          const float* __restrict__ v_in, const float* __restrict__ p_in,
          const float* __restrict__ wq, const float* __restrict__ wk,
          const float* __restrict__ wv, const float* __restrict__ wc,
          const float* __restrict__ wqb, const float* __restrict__ wkb,
          unsigned short* __restrict__ qbf, unsigned short* __restrict__ wqT,
          float* __restrict__ bq2, int n4)
{
    const int z = blockIdx.z, bx = blockIdx.x, tid = threadIdx.x;
    if (z < 4) {
        const int i = bx * 256 + tid;
        if (i >= n4) return;
        const float* s = (z == 0) ? q_in : (z == 1) ? k_in : (z == 2) ? v_in : p_in;
        float4 x = reinterpret_cast<const float4*>(s)[i];
        ushort4 o; o.x = f2bf(x.x); o.y = f2bf(x.y); o.z = f2bf(x.z); o.w = f2bf(x.w);
        reinterpret_cast<ushort4*>(qbf + (size_t)z * n4 * 4)[i] = o;
    } else if (z < 8) {
        if (bx >= 256) return;
        __shared__ unsigned short t[64][72];
        const int zz = z - 4;
        const float* src = (zz == 0) ? wq : (zz == 1) ? wk : (zz == 2) ? wv : wc;
        const float scale = (zz == 0) ? 0.125f : 1.0f;
        unsigned short* dst = wqT + (size_t)zz * DM * DM;
        const int r0 = (bx >> 4) * 64, c0 = (bx & 15) * 64;
        const int lrow = tid >> 2, lseg = (tid & 3) << 4;
        const float4* g4 = reinterpret_cast<const float4*>(src + (long)(r0 + lrow) * DM + c0 + lseg);
        alignas(16) unsigned short tmp[16];
#pragma unroll
        for (int qq = 0; qq < 4; ++qq) {
            float4 x = g4[qq];
            tmp[4*qq+0] = f2bf(x.x * scale); tmp[4*qq+1] = f2bf(x.y * scale);
            tmp[4*qq+2] = f2bf(x.z * scale); tmp[4*qq+3] = f2bf(x.w * scale);
        }
#pragma unroll
        for (int j = 0; j < 16; ++j) t[lrow][lseg + j] = tmp[j];
        __syncthreads();
#pragma unroll
        for (int j = 0; j < 16; ++j) tmp[j] = t[lseg + j][lrow];
        unsigned short* d = dst + (long)(c0 + lrow) * DM + r0 + lseg;
        *reinterpret_cast<u32x4*>(d)     = *reinterpret_cast<const u32x4*>(tmp);
        *reinterpret_cast<u32x4*>(d + 8) = *reinterpret_cast<const u32x4*>(tmp + 8);
    } else {
        if (bx >= 4) return;
        const int i = bx * 256 + tid;
        if (i < DM) { bq2[i] = wqb[i] * 0.125f; bq2[DM + i] = wkb[i]; }
    }
}

extern "C" void kernel_launch(void* const* d_in, const int* in_sizes, int n_in,
                              void* d_out, int out_size, void* d_ws, size_t ws_size,
                              hipStream_t stream)
{
    (void)in_sizes; (void)n_in; (void)out_size;
    const float* v_in = (const float*)d_in[0];
    const float* k_in = (const float*)d_in[1];
    const float* q_in = (const float*)d_in[2];
    const float* p_in = (const float*)d_in[3];
    const float* wq   = (const float*)d_in[4];
    const float* wqb  = (const float*)d_in[5];
    const float* wk   = (const float*)d_in[6];
    const float* wkb  = (const float*)d_in[7];
    const float* wvw  = (const float*)d_in[8];
    const float* wvb  = (const float*)d_in[9];
    const float* wc   = (const float*)d_in[10];
    const float* wcb  = (const float*)d_in[11];
    float* out = (float*)d_out;

    char* ws = (char*)d_ws;
    size_t off = 0;
    auto take = [&](size_t n) { char* p = ws + off; off += (n + 255) & ~(size_t)255; return p; };
    unsigned short* qbf = (unsigned short*)take((size_t)BS * DM * 2);  // qbf..pbf contiguous
    unsigned short* kbf = (unsigned short*)take((size_t)BS * DM * 2);
    unsigned short* vbf = (unsigned short*)take((size_t)BS * DM * 2);
    unsigned short* pbf = (unsigned short*)take((size_t)BS * DM * 2);
    unsigned short* wqT = (unsigned short*)take((size_t)DM * DM * 2);  // wqT..wcT contiguous
    unsigned short* wkT = (unsigned short*)take((size_t)DM * DM * 2);
    unsigned short* wvT = (unsigned short*)take((size_t)DM * DM * 2);
    unsigned short* wcT = (unsigned short*)take((size_t)DM * DM * 2);
    float*          bq2 = (float*)take((size_t)2 * DM * 4);
    float*          inv = (float*)take((size_t)NB * H * S * 4);
    unsigned short* qh  = (unsigned short*)take((size_t)BS * DM * 2);  // qh,kh contiguous
    unsigned short* kh  = (unsigned short*)take((size_t)BS * DM * 2);
    unsigned short* vhT = (unsigned short*)take((size_t)BS * DM * 2);
    unsigned short* ao  = (unsigned short*)take((size_t)BS * DM * 2);
    const size_t ssz = (size_t)NB * HSS * 2;
    unsigned short* B1 = (unsigned short*)take(ssz);
    unsigned short* B2 = (unsigned short*)take(ssz);
    unsigned short* B3 = (unsigned short*)take(ssz);
    const bool dual = (ws_size >= off + ssz);          // 4th S x S buffer fits?
    unsigned short* B4 = dual ? (unsigned short*)take(ssz) : nullptr;
    (void)kbf; (void)wkT;

    const int n4 = BS * DM / 4;
    const dim3 b256(256), b128(128), b64(64);

    // merged casts + weight transposes + bias pack (1 launch)
    prep<<<dim3(n4 / 256, 1, 9), b256, 0, stream>>>(
        q_in, k_in, v_in, p_in, wq, wk, wvw, wc, wqb, wkb, qbf, wqT, bq2, n4);

    // q,k projections merged over z (alpha folded into wqT/bq2), 64x128 tiles
    gemmT<64,128,EPI_BFB,false,false,false,false><<<dim3(8, 32, 2), b128, 0, stream>>>(
        qbf, 0, (long)BS*DM, DM,  wqT, 0, (long)DM*DM, DM,  qh, nullptr, 0, (long)BS*DM, DM,
        bq2, DM, DM, DM);
    // vhT[b][dm][t] = (v@wv + b)^T, 64x128 tiles
    gemmT<64,128,EPI_VTB,false,false,false,false><<<dim3(8, 16, 2), b128, 0, stream>>>(
        wvT, 0, 0, DM,  vbf, 0, SDM, DM,  vhT, nullptr, 0, (long)DM*S, S,
        wvb, 0, DM, S);

    unsigned short *pbuf, *ptbuf, *sqkbuf, *ebuf, *s2buf;
    if (dual) {
        // merged: P -> B1, P^T -> B2, sQK -> B3 in ONE launch
        packsqk<<<dim3(8, 8, 64), b256, 0, stream>>>(qh, pbf, kh, B1, B2, B3);
        pbuf = B1; ptbuf = B2; sqkbuf = B3; ebuf = B4; s2buf = B3;
    } else {
        // packT[s][t] = elu(ph[s].qh[t])+1 -> B1 ; sQK -> B2
        gemmT<128,128,EPI_PACK,false,false,true,false><<<dim3(8, 8, 32), b256, 0, stream>>>(
            pbf, SDM, 64, DM,  qh, SDM, 64, DM,  B1, nullptr, HSS, SS, S,  wvb, 0, 64, S);
        gemmT<128,128,EPI_MASK,false,true,true,false><<<dim3(8, 8, 32), b256, 0, stream>>>(
            qh, SDM, 64, DM,  kh, SDM, 64, DM,  B2, nullptr, HSS, SS, S,  wvb, 0, 64, S);
        ptbuf = B1; sqkbuf = B2; ebuf = B3; pbuf = B1; s2buf = B2;
    }
    // E = exp(sQK @ P) (B = P^T rows j), causal-K -> ebuf (bf16, unnormalized)
    gemmU<<<dim3(8, 8, 32), b256, 0, stream>>>(sqkbuf, ptbuf, ebuf);
    // inv2[row] = 1 / (rowsum(E) * (t+1))
    rowsum_inv<<<dim3(NB*H*S/4), b256, 0, stream>>>(ebuf, inv);
    if (!dual) {
        // pack[t][s] = elu(qh.ph)+1 -> B1 (packT dead)
        gemmT<128,128,EPI_PACK,false,false,true,false><<<dim3(8, 8, 32), b256, 0, stream>>>(
            qh, SDM, 64, DM,  pbf, SDM, 64, DM,  B1, nullptr, HSS, SS, S,  wvb, 0, 64, S);
    }
    // s2[t][s] = (E[t,:].P[s,:]) * inv2[t], causal-skip -> s2buf (sQK dead)
    gemmV<<<dim3(8, 8, 32), b256, 0, stream>>>(ebuf, pbuf, s2buf, inv);
    // attn_out[t][d] = s2 @ vh (B = vhT head-slice [d][s]), 64x64 tiles (512
    // blocks = 2/CU, 1 wave each), causal-K longest-first
    gemmT<64,64,EPI_BF,true,false,false,true><<<dim3(1, 16, 32), b64, 0, stream>>>(
        s2buf, HSS, SS, S,  vhT, (long)DM*S, (long)64*S, S,  ao, nullptr, SDM, 64, DM,
        wvb, 0, S, 64);
    // out = ao @ wc + b (f32), 64x128 tiles
    gemmT<64,128,EPI_OUT,false,false,false,false><<<dim3(8, 32, 1), b128, 0, stream>>>(
        ao, 0, 0, DM,  wcT, 0, 0, DM,  out, nullptr, 0, 0, DM,  wcb, 0, DM, DM);
}

// Round 13
// 274.625 us; speedup vs baseline: 1.1633x; 1.0741x over previous
//
#include <hip/hip_runtime.h>

#define DEVI static __device__ __forceinline__

using s16x8 = __attribute__((ext_vector_type(8))) short;
using f32x4 = __attribute__((ext_vector_type(4))) float;
using u32x4 = __attribute__((ext_vector_type(4))) unsigned int;

static constexpr int H  = 16;
static constexpr int S  = 1024;
static constexpr int DM = 1024;
static constexpr int NB = 2;          // batch
static constexpr int BS = NB * S;     // 2048
static constexpr long SS  = (long)S * S;
static constexpr long HSS = (long)H * SS;
static constexpr long SDM = (long)S * DM;

DEVI unsigned short f2bf(float f) {
    union { float f; unsigned u; } c; c.f = f;
    c.u += 0x7FFFu + ((c.u >> 16) & 1u);   // RNE
    return (unsigned short)(c.u >> 16);
}
DEVI float bf2f(unsigned short v) {
    union { unsigned u; float f; } c; c.u = ((unsigned)v) << 16;
    return c.f;
}

// async global->LDS, 16 bytes per lane; lds dest = wave-uniform base + lane*16
DEVI void gload16(const unsigned short* g, unsigned short* l) {
    __builtin_amdgcn_global_load_lds(
        (const __attribute__((address_space(1))) unsigned int*)g,
        (__attribute__((address_space(3))) unsigned int*)l, 16, 0, 0);
}

enum { EPI_BFB = 0, EPI_VTB, EPI_PACK, EPI_PACK2, EPI_MASK, EPI_BF, EPI_OUT };

// ---------------------------------------------------------------------------
// gemmU: dedicated unpack kernel (body = r11 verbatim). E = exp(sQK @ P^T),
// causal-K. Epilogue additionally writes CONTENTION-FREE per-slice row sums:
// psum[bz][bx*2+(w&1)][row] — plain stores, no atomics (r10 lesson: atomics
// cost 11.5us; plain slices ~1.5us). Grid (8,8,32).
// ---------------------------------------------------------------------------
__global__ __launch_bounds__(256)
void gemmU(const unsigned short* __restrict__ Aall,
           const unsigned short* __restrict__ Ball,
           unsigned short* __restrict__ Oall, float* __restrict__ psum)
{
    const int L = (int)blockIdx.x + ((int)blockIdx.y << 3) + ((int)blockIdx.z << 6);
    const int g = L & 7, r = L >> 3;
    const int bz = g + ((r >> 6) << 3);
    const int bx = r & 7;
    const int by = 7 - ((r >> 3) & 7);           // longest-K first
    const int m0 = by * 128, n0 = bx * 128;
    const unsigned short* Ap = Aall + (long)bz * SS;
    const unsigned short* Bp = Ball + (long)bz * SS;

    __shared__ alignas(16) unsigned short lA[128 * 64];
    __shared__ alignas(16) unsigned short lB[128 * 64];

    const int tid = threadIdx.x, w = tid >> 6, lane = tid & 63;
    const int lr = lane & 15, lg = lane >> 4;
    const int wm = (w >> 1) << 6, wn = (w & 1) << 6;

    const unsigned short* gA[4]; const unsigned short* gB[4]; int lo[4];
#pragma unroll
    for (int i = 0; i < 4; ++i) {
        const int q = (i * 4 + w) * 64 + lane, row = q >> 3, slot = q & 7;
        const int gs = (slot ^ (row & 7)) * 8;
        gA[i] = Ap + (long)(m0 + row) * S + gs;
        gB[i] = Bp + (long)(n0 + row) * S + gs;
        lo[i] = (i * 4 + w) * 512;
    }

    int abase[4], axor[4], bbase[4], bxor[4];
#pragma unroll
    for (int f = 0; f < 4; ++f) {
        const int ra = wm + f * 16 + lr;
        abase[f] = ra * 64; axor[f] = (ra & 7) * 8;
        const int rb = wn + f * 16 + lr;
        bbase[f] = rb * 64; bxor[f] = (rb & 7) * 8;
    }

    f32x4 acc[4][4] = {};
    const int Keff = m0 + 128;                   // causal-K cap

    for (int k0 = 0; k0 < Keff; k0 += 64) {
#pragma unroll
        for (int i = 0; i < 4; ++i) {
            gload16(gA[i] + k0, &lA[lo[i]]);
            gload16(gB[i] + k0, &lB[lo[i]]);
        }
        __syncthreads();
#pragma unroll
        for (int kk = 0; kk < 64; kk += 32) {
            s16x8 af[4], bv[4];
#pragma unroll
            for (int f = 0; f < 4; ++f) {
                af[f] = *reinterpret_cast<const s16x8*>(&lA[abase[f] + ((kk + 8 * lg) ^ axor[f])]);
                bv[f] = *reinterpret_cast<const s16x8*>(&lB[bbase[f] + ((kk + 8 * lg) ^ bxor[f])]);
            }
#pragma unroll
            for (int fm = 0; fm < 4; ++fm)
#pragma unroll
                for (int fn = 0; fn < 4; ++fn)
                    acc[fm][fn] = __builtin_amdgcn_mfma_f32_16x16x32_bf16(af[fm], bv[fn], acc[fm][fn], 0, 0, 0);
        }
        __syncthreads();
    }

    const long obase = (long)bz * SS;
    float* ps = psum + ((long)bz * 16 + bx * 2 + (w & 1)) * S;
#pragma unroll
    for (int fm = 0; fm < 4; ++fm) {
        const int t0 = m0 + wm + fm * 16 + lg * 4;
        float es[4] = {0.f, 0.f, 0.f, 0.f};
#pragma unroll
        for (int fn = 0; fn < 4; ++fn) {
            const int gn = n0 + wn + fn * 16 + lr;
#pragma unroll
            for (int rr = 0; rr < 4; ++rr) {
                const float e = __expf(acc[fm][fn][rr]);
                Oall[obase + (long)(t0 + rr) * S + gn] = f2bf(e);
                es[rr] += e;
            }
        }
#pragma unroll
        for (int rr = 0; rr < 4; ++rr) {
            float s = es[rr];
            s += __shfl_xor(s, 1); s += __shfl_xor(s, 2);
            s += __shfl_xor(s, 4); s += __shfl_xor(s, 8);
            if (lr == 0) ps[t0 + rr] = s;        // plain store, zero contention
        }
    }
}

// ---------------------------------------------------------------------------
// gemmV: dedicated s2 kernel (r11 VERBATIM — 63.7us). s2 = (E.P) * inv2[t],
// masked; inv2[t] = 1/(rowsum(E)*(t+1)). Grid (8,8,32).
// ---------------------------------------------------------------------------
__global__ __launch_bounds__(256)
void gemmV(const unsigned short* __restrict__ Aall,
           const unsigned short* __restrict__ Ball,
           unsigned short* __restrict__ Oall, const float* __restrict__ inv2)
{
    const int L = (int)blockIdx.x + ((int)blockIdx.y << 3) + ((int)blockIdx.z << 6);
    const int g = L & 7, r = L >> 3;
    const int bz = g + ((r >> 6) << 3);
    const int bx = r & 7;
    const int by = 7 - ((r >> 3) & 7);
    const int m0 = by * 128, n0 = bx * 128;
    if (n0 > m0 + 127) return;
    const unsigned short* Ap = Aall + (long)bz * SS;
    const unsigned short* Bp = Ball + (long)bz * SS;

    __shared__ alignas(16) unsigned short lA[128 * 64];
    __shared__ alignas(16) unsigned short lB[128 * 64];

    const int tid = threadIdx.x, w = tid >> 6, lane = tid & 63;
    const int lr = lane & 15, lg = lane >> 4;
    const int wm = (w >> 1) << 6, wn = (w & 1) << 6;

    const unsigned short* gA[4]; const unsigned short* gB[4]; int lo[4];
#pragma unroll
    for (int i = 0; i < 4; ++i) {
        const int q = (i * 4 + w) * 64 + lane, row = q >> 3, slot = q & 7;
        const int gs = (slot ^ (row & 7)) * 8;
        gA[i] = Ap + (long)(m0 + row) * S + gs;
        gB[i] = Bp + (long)(n0 + row) * S + gs;
        lo[i] = (i * 4 + w) * 512;
    }

    int abase[4], axor[4], bbase[4], bxor[4];
#pragma unroll
    for (int f = 0; f < 4; ++f) {
        const int ra = wm + f * 16 + lr;
        abase[f] = ra * 64; axor[f] = (ra & 7) * 8;
        const int rb = wn + f * 16 + lr;
        bbase[f] = rb * 64; bxor[f] = (rb & 7) * 8;
    }

    f32x4 acc[4][4] = {};

    for (int k0 = 0; k0 < S; k0 += 64) {
#pragma unroll
        for (int i = 0; i < 4; ++i) {
            gload16(gA[i] + k0, &lA[lo[i]]);
            gload16(gB[i] + k0, &lB[lo[i]]);
        }
        __syncthreads();
#pragma unroll
        for (int kk = 0; kk < 64; kk += 32) {
            s16x8 af[4], bv[4];
#pragma unroll
            for (int f = 0; f < 4; ++f) {
                af[f] = *reinterpret_cast<const s16x8*>(&lA[abase[f] + ((kk + 8 * lg) ^ axor[f])]);
                bv[f] = *reinterpret_cast<const s16x8*>(&lB[bbase[f] + ((kk + 8 * lg) ^ bxor[f])]);
            }
#pragma unroll
            for (int fm = 0; fm < 4; ++fm)
#pragma unroll
                for (int fn = 0; fn < 4; ++fn)
                    acc[fm][fn] = __builtin_amdgcn_mfma_f32_16x16x32_bf16(af[fm], bv[fn], acc[fm][fn], 0, 0, 0);
        }
        __syncthreads();
    }

    const long obase = (long)bz * SS;
#pragma unroll
    for (int fm = 0; fm < 4; ++fm) {
        const int t0 = m0 + wm + fm * 16 + lg * 4;
        float rec[4];
#pragma unroll
        for (int rr = 0; rr < 4; ++rr)
            rec[rr] = inv2[(long)bz * S + t0 + rr];
#pragma unroll
        for (int fn = 0; fn < 4; ++fn) {
            const int gn = n0 + wn + fn * 16 + lr;
#pragma unroll
            for (int rr = 0; rr < 4; ++rr) {
                const int gm = t0 + rr;
                const float vv = (gn <= gm) ? acc[fm][fn][rr] * rec[rr] : 0.f;
                Oall[obase + (long)gm * S + gn] = f2bf(vv);
            }
        }
    }
}

// sumfin: inv2[bz*S+row] = 1 / (sum_{16 slices} psum * (row+1)). 2 MB read.
__global__ __launch_bounds__(256)
void sumfin(const float* __restrict__ psum, float* __restrict__ inv2)
{
    const long i = (long)blockIdx.x * 256 + threadIdx.x;   // 0..32767
    const long bz = i >> 10, row = i & 1023;
    const float* p = psum + (bz * 16) * S + row;
    float s = 0.f;
#pragma unroll
    for (int k = 0; k < 16; ++k) s += p[(long)k * S];
    inv2[bz * S + row] = 1.f / (s * (float)(row + 1));
}

// ---------------------------------------------------------------------------
// proj3: merged q-proj / k-proj / vhT. Grid (8,32,3), 128 thr, 64x128 tile,
// m97 loop. z=0: qh = q@wqT + bq2[0] (alpha folded); z=1: kh; z=2: vhT
// (A=wvT, B=v batch by>>4, bias by output row). All lds/ldo = 1024.
// ---------------------------------------------------------------------------
__global__ __launch_bounds__(128)
void proj3(const unsigned short* __restrict__ qbf,
           const unsigned short* __restrict__ wqT,
           const unsigned short* __restrict__ vbf,
           const unsigned short* __restrict__ wvT,
           const float* __restrict__ bq2, const float* __restrict__ wvb,
           unsigned short* __restrict__ qh, unsigned short* __restrict__ vhT)
{
    const int z = blockIdx.z, bx = blockIdx.x, by = blockIdx.y;
    const unsigned short *Ap, *Bp; unsigned short* Op;
    const float* bi; int m0; bool vt;
    if (z < 2) {
        Ap = qbf + (long)z * BS * DM;  Bp = wqT + (long)z * DM * DM;
        Op = qh  + (long)z * BS * DM;  bi = bq2 + z * DM;
        m0 = by * 64; vt = false;
    } else {
        const int zb = by >> 4;
        Ap = wvT;                      Bp = vbf + (long)zb * SDM;
        Op = vhT + (long)zb * (long)DM * S;  bi = wvb;
        m0 = (by & 15) * 64; vt = true;
    }
    const int n0 = bx * 128;

    __shared__ alignas(16) unsigned short lA[64 * 64];
    __shared__ alignas(16) unsigned short lB[128 * 64];

    const int tid = threadIdx.x, w = tid >> 6, lane = tid & 63;
    const int lr = lane & 15, lg = lane >> 4;
    const int wn = (w & 1) << 6;                 // wm = 0

    const unsigned short* gA[4]; int loA[4];
    const unsigned short* gB[8]; int loB[8];
#pragma unroll
    for (int i = 0; i < 4; ++i) {
        const int q = i * 128 + tid, row = q >> 3, slot = q & 7;
        gA[i]  = Ap + (long)(m0 + row) * DM + ((slot ^ (row & 7)) * 8);
        loA[i] = (i * 2 + w) * 512;
    }
#pragma unroll
    for (int i = 0; i < 8; ++i) {
        const int q = i * 128 + tid, row = q >> 3, slot = q & 7;
        gB[i]  = Bp + (long)(n0 + row) * DM + ((slot ^ (row & 7)) * 8);
        loB[i] = (i * 2 + w) * 512;
    }

    int abase[4], axor[4], bbase[4], bxor[4];
#pragma unroll
    for (int f = 0; f < 4; ++f) {
        const int ra = f * 16 + lr;
        abase[f] = ra * 64; axor[f] = (ra & 7) * 8;
        const int rb = wn + f * 16 + lr;
        bbase[f] = rb * 64; bxor[f] = (rb & 7) * 8;
    }

    f32x4 acc[4][4] = {};

    for (int k0 = 0; k0 < DM; k0 += 64) {
#pragma unroll
        for (int i = 0; i < 4; ++i) gload16(gA[i] + k0, &lA[loA[i]]);
#pragma unroll
        for (int i = 0; i < 8; ++i) gload16(gB[i] + k0, &lB[loB[i]]);
        __syncthreads();
#pragma unroll
        for (int kk = 0; kk < 64; kk += 32) {
            s16x8 af[4], bv[4];
#pragma unroll
            for (int f = 0; f < 4; ++f) {
                af[f] = *reinterpret_cast<const s16x8*>(&lA[abase[f] + ((kk + 8 * lg) ^ axor[f])]);
                bv[f] = *reinterpret_cast<const s16x8*>(&lB[bbase[f] + ((kk + 8 * lg) ^ bxor[f])]);
            }
#pragma unroll
            for (int fm = 0; fm < 4; ++fm)
#pragma unroll
                for (int fn = 0; fn < 4; ++fn)
                    acc[fm][fn] = __builtin_amdgcn_mfma_f32_16x16x32_bf16(af[fm], bv[fn], acc[fm][fn], 0, 0, 0);
        }
        __syncthreads();
    }

#pragma unroll
    for (int fm = 0; fm < 4; ++fm)
#pragma unroll
        for (int fn = 0; fn < 4; ++fn) {
            const int t0 = m0 + fm * 16 + lg * 4;
            const int gn = n0 + wn + fn * 16 + lr;
#pragma unroll
            for (int rr = 0; rr < 4; ++rr) {
                const int gm = t0 + rr;
                const float vv = acc[fm][fn][rr] + (vt ? bi[gm] : bi[gn]);
                Op[(long)gm * 1024 + gn] = f2bf(vv);
            }
        }
}

// ---------------------------------------------------------------------------
// gemmT: TMxTN-tile m97 loop (attn_out, out-proj, non-dual fallback)
// ---------------------------------------------------------------------------
template<int TM, int TN, int EPI, bool CK, bool CS, bool SWZ, bool REVY>
__global__ __launch_bounds__((TM/64)*(TN/64)*64)
void gemmT(const unsigned short* __restrict__ Aall, long a_sb, long a_sh, int lda,
           const unsigned short* __restrict__ Ball, long b_sb, long b_sh, int ldb,
           void* __restrict__ Oall, void* __restrict__ O2, long o_sb, long o_sh, int ldo,
           const float* __restrict__ bias, int bstride, int K, int NV)
{
    constexpr int WN = TN / 64, WM = TM / 64, NWV = WM * WN, NTHR = NWV * 64;
    constexpr int IA = (TM * 8) / NTHR, IB = (TN * 8) / NTHR;

    int bx, by, bz;
    if (SWZ) {   // grid must be (8,8,32)
        const int L = (int)blockIdx.x + ((int)blockIdx.y << 3) + ((int)blockIdx.z << 6);
        const int g = L & 7, r = L >> 3;
        bz = g + ((r >> 6) << 3);
        bx = r & 7;
        by = 7 - ((r >> 3) & 7);                 // longest-K first
    } else {
        bx = blockIdx.x;
        by = REVY ? (int)gridDim.y - 1 - (int)blockIdx.y : (int)blockIdx.y;
        bz = blockIdx.z;
    }
    const int m0 = by * TM, n0 = bx * TN;
    if (CS && n0 > m0 + TM - 1) return;
    const int zb = bz >> 4, zh = bz & 15;
    const unsigned short* Ap = Aall + (long)zb * a_sb + (long)zh * a_sh;
    const unsigned short* Bp = Ball + (long)zb * b_sb + (long)zh * b_sh;
    const float* bi = bias + (long)zh * bstride;

    __shared__ alignas(16) unsigned short lA[TM * 64];
    __shared__ alignas(16) unsigned short lB[TN * 64];

    const int tid = threadIdx.x, w = tid >> 6, lane = tid & 63;
    const int lr = lane & 15, lg = lane >> 4;
    const int wm = (w / WN) * 64, wn = (w % WN) * 64;

    const unsigned short* gA[IA]; int loA[IA];
    const unsigned short* gB[IB]; int loB[IB];
#pragma unroll
    for (int i = 0; i < IA; ++i) {
        const int q = i * NTHR + tid, row = q >> 3, slot = q & 7;
        gA[i]  = Ap + (long)(m0 + row) * lda + ((slot ^ (row & 7)) * 8);
        loA[i] = (i * NWV + w) * 512;
    }
#pragma unroll
    for (int i = 0; i < IB; ++i) {
        const int q = i * NTHR + tid, row = q >> 3, slot = q & 7;
        int rb = n0 + row; if (rb >= NV) rb = NV - 1;
        gB[i]  = Bp + (long)rb * ldb + ((slot ^ (row & 7)) * 8);
        loB[i] = (i * NWV + w) * 512;
    }

    int abase[4], axor[4], bbase[4], bxor[4];
#pragma unroll
    for (int f = 0; f < 4; ++f) {
        const int ra = wm + f * 16 + lr;
        abase[f] = ra * 64; axor[f] = (ra & 7) * 8;
        const int rb = wn + f * 16 + lr;
        bbase[f] = rb * 64; bxor[f] = (rb & 7) * 8;
    }

    f32x4 acc[4][4] = {};
    const int Keff = CK ? ((K < m0 + TM) ? K : m0 + TM) : K;

    for (int k0 = 0; k0 < Keff; k0 += 64) {
#pragma unroll
        for (int i = 0; i < IA; ++i) gload16(gA[i] + k0, &lA[loA[i]]);
#pragma unroll
        for (int i = 0; i < IB; ++i) gload16(gB[i] + k0, &lB[loB[i]]);
        __syncthreads();
#pragma unroll
        for (int kk = 0; kk < 64; kk += 32) {
            s16x8 af[4], bv[4];
#pragma unroll
            for (int f = 0; f < 4; ++f) {
                af[f] = *reinterpret_cast<const s16x8*>(&lA[abase[f] + ((kk + 8 * lg) ^ axor[f])]);
                bv[f] = *reinterpret_cast<const s16x8*>(&lB[bbase[f] + ((kk + 8 * lg) ^ bxor[f])]);
            }
#pragma unroll
            for (int fm = 0; fm < 4; ++fm)
#pragma unroll
                for (int fn = 0; fn < 4; ++fn)
                    acc[fm][fn] = __builtin_amdgcn_mfma_f32_16x16x32_bf16(af[fm], bv[fn], acc[fm][fn], 0, 0, 0);
        }
        __syncthreads();
    }

    const long obase = (long)zb * o_sb + (long)zh * o_sh;
#pragma unroll
    for (int fm = 0; fm < 4; ++fm)
#pragma unroll
        for (int fn = 0; fn < 4; ++fn) {
            const int t0 = m0 + wm + fm * 16 + lg * 4;
            const int gn = n0 + wn + fn * 16 + lr;
            if (gn >= NV) continue;
            if constexpr (EPI == EPI_PACK2) {             // dual store: P and P^T
                ushort4 pt;
                unsigned short* o1 = (unsigned short*)Oall;
                unsigned short* o2 = (unsigned short*)O2;
#pragma unroll
                for (int r = 0; r < 4; ++r) {
                    float vv = acc[fm][fn][r];
                    vv = vv > 0.f ? vv + 1.f : __expf(vv);   // elu(x)+1
                    const unsigned short b = f2bf(vv);
                    o1[obase + (long)(t0 + r) * ldo + gn] = b;
                    ((unsigned short*)&pt)[r] = b;
                }
                *reinterpret_cast<ushort4*>(&o2[obase + (long)gn * ldo + t0]) = pt;
            } else {
#pragma unroll
                for (int r = 0; r < 4; ++r) {
                    const int gm = t0 + r;
                    float vv = acc[fm][fn][r];
                    const long o = obase + (long)gm * ldo + gn;
                    if constexpr (EPI == EPI_BFB) {
                        ((unsigned short*)Oall)[o] = f2bf(vv + bi[gn]);
                    } else if constexpr (EPI == EPI_VTB) {
                        ((unsigned short*)Oall)[o] = f2bf(vv + bi[gm]);
                    } else if constexpr (EPI == EPI_PACK) {
                        vv = vv > 0.f ? vv + 1.f : __expf(vv);
                        ((unsigned short*)Oall)[o] = f2bf(vv);
                    } else if constexpr (EPI == EPI_MASK) {
                        vv = (gn <= gm) ? vv / (float)(gm + 1) : 0.f;
                        ((unsigned short*)Oall)[o] = f2bf(vv);
                    } else if constexpr (EPI == EPI_BF) {
                        ((unsigned short*)Oall)[o] = f2bf(vv);
                    } else { // EPI_OUT
                        ((float*)Oall)[o] = vv + bi[gn];
                    }
                }
            }
        }
}

// ---------------------------------------------------------------------------
// packsqk: merged pack2 + sQK (both 128x128-tile, K=64). Grid (8,8,64):
// z-swizzled; job = high bit (0: P/P^T dual store, 1: masked QK^T causal-skip)
// ---------------------------------------------------------------------------
__global__ __launch_bounds__(256)
void packsqk(const unsigned short* __restrict__ qh,
             const unsigned short* __restrict__ pbf,
             const unsigned short* __restrict__ kh,
             unsigned short* __restrict__ P, unsigned short* __restrict__ PT,
             unsigned short* __restrict__ SQ)
{
    const int L = (int)blockIdx.x + ((int)blockIdx.y << 3) + ((int)blockIdx.z << 6);
    const int g = L & 7, r = L >> 3;
    const int bzz = g + ((r >> 6) << 3);          // 0..63
    const int bx = r & 7, by = 7 - ((r >> 3) & 7);
    const int job = bzz >> 5, zz = bzz & 31;
    const int m0 = by * 128, n0 = bx * 128;
    if (job && n0 > m0 + 127) return;
    const int zb = zz >> 4, zh = zz & 15;
    const unsigned short* Ap = qh + (long)zb * SDM + zh * 64;
    const unsigned short* Bp = (job ? kh : pbf) + (long)zb * SDM + zh * 64;

    __shared__ alignas(16) unsigned short lA[128 * 64];
    __shared__ alignas(16) unsigned short lB[128 * 64];

    const int tid = threadIdx.x, w = tid >> 6, lane = tid & 63;
    const int lr = lane & 15, lg = lane >> 4;
    const int wm = (w >> 1) << 6, wn = (w & 1) << 6;

#pragma unroll
    for (int i = 0; i < 4; ++i) {
        const int q = i * 256 + tid, row = q >> 3, slot = q & 7;
        const int gs = (slot ^ (row & 7)) * 8;
        gload16(Ap + (long)(m0 + row) * DM + gs, &lA[(i * 4 + w) * 512]);
        gload16(Bp + (long)(n0 + row) * DM + gs, &lB[(i * 4 + w) * 512]);
    }
    __syncthreads();

    f32x4 acc[4][4] = {};
#pragma unroll
    for (int kk = 0; kk < 64; kk += 32) {
        s16x8 af[4], bv[4];
#pragma unroll
        for (int f = 0; f < 4; ++f) {
            const int ra = wm + f * 16 + lr;
            af[f] = *reinterpret_cast<const s16x8*>(&lA[ra * 64 + ((kk + 8 * lg) ^ ((ra & 7) * 8))]);
            const int rb = wn + f * 16 + lr;
            bv[f] = *reinterpret_cast<const s16x8*>(&lB[rb * 64 + ((kk + 8 * lg) ^ ((rb & 7) * 8))]);
        }
#pragma unroll
        for (int fm = 0; fm < 4; ++fm)
#pragma unroll
            for (int fn = 0; fn < 4; ++fn)
                acc[fm][fn] = __builtin_amdgcn_mfma_f32_16x16x32_bf16(af[fm], bv[fn], acc[fm][fn], 0, 0, 0);
    }

    const long obase = (long)zz * SS;
#pragma unroll
    for (int fm = 0; fm < 4; ++fm)
#pragma unroll
        for (int fn = 0; fn < 4; ++fn) {
            const int t0 = m0 + wm + fm * 16 + lg * 4;
            const int gn = n0 + wn + fn * 16 + lr;
            if (job == 0) {                        // P and P^T dual store
                ushort4 pt;
#pragma unroll
                for (int rr = 0; rr < 4; ++rr) {
                    float vv = acc[fm][fn][rr];
                    vv = vv > 0.f ? vv + 1.f : __expf(vv);
                    const unsigned short b = f2bf(vv);
                    P[obase + (long)(t0 + rr) * S + gn] = b;
                    ((unsigned short*)&pt)[rr] = b;
                }
                *reinterpret_cast<ushort4*>(&PT[obase + (long)gn * S + t0]) = pt;
            } else {                               // masked QK^T
#pragma unroll
                for (int rr = 0; rr < 4; ++rr) {
                    const int gm = t0 + rr;
                    float vv = acc[fm][fn][rr];
                    vv = (gn <= gm) ? vv / (float)(gm + 1) : 0.f;
                    SQ[obase + (long)gm * S + gn] = f2bf(vv);
                }
            }
        }
}

// ---------------------------------------------------------------------------
// prep: merged input casts (z=0..3), weight transposes (z=4..7), bias pack (z=8)
// grid (2048, 1, 9) x 256 threads
// ---------------------------------------------------------------------------
__global__ __launch_bounds__(256)
void prep(const float* __restrict__ q_in, const float* __restrict__ k_in,
          const float* __restrict__ v_in, const float* __restrict__ p_in,
          const float* __restrict__ wq, const float* __restrict__ wk,
          const float* __restrict__ wv, const float* __restrict__ wc,
          const float* __restrict__ wqb, const float* __restrict__ wkb,
          unsigned short* __restrict__ qbf, unsigned short* __restrict__ wqT,
          float* __restrict__ bq2, int n4)
{
    const int z = blockIdx.z, bx = blockIdx.x, tid = threadIdx.x;
    if (z < 4) {
        const int i = bx * 256 + tid;
        if (i >= n4) return;
        const float* s = (z == 0) ? q_in : (z == 1) ? k_in : (z == 2) ? v_in : p_in;
        float4 x = reinterpret_cast<const float4*>(s)[i];
        ushort4 o; o.x = f2bf(x.x); o.y = f2bf(x.y); o.z = f2bf(x.z); o.w = f2bf(x.w);
        reinterpret_cast<ushort4*>(qbf + (size_t)z * n4 * 4)[i] = o;
    } else if (z < 8) {
        if (bx >= 256) return;
        __shared__ unsigned short t[64][72];
        const int zz = z - 4;
        const float* src = (zz == 0) ? wq : (zz == 1) ? wk : (zz == 2) ? wv : wc;
        const float scale = (zz == 0) ? 0.125f : 1.0f;
        unsigned short* dst = wqT + (size_t)zz * DM * DM;
        const int r0 = (bx >> 4) * 64, c0 = (bx & 15) * 64;
        const int lrow = tid >> 2, lseg = (tid & 3) << 4;
        const float4* g4 = reinterpret_cast<const float4*>(src + (long)(r0 + lrow) * DM + c0 + lseg);
        alignas(16) unsigned short tmp[16];
#pragma unroll
        for (int qq = 0; qq < 4; ++qq) {
            float4 x = g4[qq];
            tmp[4*qq+0] = f2bf(x.x * scale); tmp[4*qq+1] = f2bf(x.y * scale);
            tmp[4*qq+2] = f2bf(x.z * scale); tmp[4*qq+3] = f2bf(x.w * scale);
        }
#pragma unroll
        for (int j = 0; j < 16; ++j) t[lrow][lseg + j] = tmp[j];
        __syncthreads();
#pragma unroll
        for (int j = 0; j < 16; ++j) tmp[j] = t[lseg + j][lrow];
        unsigned short* d = dst + (long)(c0 + lrow) * DM + r0 + lseg;
        *reinterpret_cast<u32x4*>(d)     = *reinterpret_cast<const u32x4*>(tmp);
        *reinterpret_cast<u32x4*>(d + 8) = *reinterpret_cast<const u32x4*>(tmp + 8);
    } else {
        if (bx >= 4) return;
        const int i = bx * 256 + tid;
        if (i < DM) { bq2[i] = wqb[i] * 0.125f; bq2[DM + i] = wkb[i]; }
    }
}

extern "C" void kernel_launch(void* const* d_in, const int* in_sizes, int n_in,
                              void* d_out, int out_size, void* d_ws, size_t ws_size,
                              hipStream_t stream)
{
    (void)in_sizes; (void)n_in; (void)out_size;
    const float* v_in = (const float*)d_in[0];
    const float* k_in = (const float*)d_in[1];
    const float* q_in = (const float*)d_in[2];
    const float* p_in = (const float*)d_in[3];
    const float* wq   = (const float*)d_in[4];
    const float* wqb  = (const float*)d_in[5];
    const float* wk   = (const float*)d_in[6];
    const float* wkb  = (const float*)d_in[7];
    const float* wvw  = (const float*)d_in[8];
    const float* wvb  = (const float*)d_in[9];
    const float* wc   = (const float*)d_in[10];
    const float* wcb  = (const float*)d_in[11];
    float* out = (float*)d_out;

    char* ws = (char*)d_ws;
    size_t off = 0;
    auto take = [&](size_t n) { char* p = ws + off; off += (n + 255) & ~(size_t)255; return p; };
    unsigned short* qbf = (unsigned short*)take((size_t)BS * DM * 2);  // qbf..pbf contiguous
    unsigned short* kbf = (unsigned short*)take((size_t)BS * DM * 2);
    unsigned short* vbf = (unsigned short*)take((size_t)BS * DM * 2);
    unsigned short* pbf = (unsigned short*)take((size_t)BS * DM * 2);
    unsigned short* wqT = (unsigned short*)take((size_t)DM * DM * 2);  // wqT..wcT contiguous
    unsigned short* wkT = (unsigned short*)take((size_t)DM * DM * 2);
    unsigned short* wvT = (unsigned short*)take((size_t)DM * DM * 2);
    unsigned short* wcT = (unsigned short*)take((size_t)DM * DM * 2);
    float*          bq2 = (float*)take((size_t)2 * DM * 4);
    float*          inv = (float*)take((size_t)NB * H * S * 4);
    float*          psum= (float*)take((size_t)NB * H * 16 * S * 4);   // 2 MB
    unsigned short* qh  = (unsigned short*)take((size_t)BS * DM * 2);  // qh,kh contiguous
    unsigned short* kh  = (unsigned short*)take((size_t)BS * DM * 2);
    unsigned short* vhT = (unsigned short*)take((size_t)BS * DM * 2);
    unsigned short* ao  = (unsigned short*)take((size_t)BS * DM * 2);
    const size_t ssz = (size_t)NB * HSS * 2;
    unsigned short* B1 = (unsigned short*)take(ssz);
    unsigned short* B2 = (unsigned short*)take(ssz);
    unsigned short* B3 = (unsigned short*)take(ssz);
    const bool dual = (ws_size >= off + ssz);          // 4th S x S buffer fits?
    unsigned short* B4 = dual ? (unsigned short*)take(ssz) : nullptr;
    (void)kbf; (void)wkT;

    const int n4 = BS * DM / 4;
    const dim3 b256(256), b128(128), b64(64);

    // merged casts + weight transposes + bias pack (1 launch)
    prep<<<dim3(n4 / 256, 1, 9), b256, 0, stream>>>(
        q_in, k_in, v_in, p_in, wq, wk, wvw, wc, wqb, wkb, qbf, wqT, bq2, n4);

    // merged q-proj / k-proj / vhT (1 launch, 768 blocks)
    proj3<<<dim3(8, 32, 3), b128, 0, stream>>>(
        qbf, wqT, vbf, wvT, bq2, wvb, qh, vhT);

    unsigned short *pbuf, *ptbuf, *sqkbuf, *ebuf, *s2buf;
    if (dual) {
        // merged: P -> B1, P^T -> B2, sQK -> B3 in ONE launch
        packsqk<<<dim3(8, 8, 64), b256, 0, stream>>>(qh, pbf, kh, B1, B2, B3);
        pbuf = B1; ptbuf = B2; sqkbuf = B3; ebuf = B4; s2buf = B3;
    } else {
        // packT[s][t] = elu(ph[s].qh[t])+1 -> B1 ; sQK -> B2
        gemmT<128,128,EPI_PACK,false,false,true,false><<<dim3(8, 8, 32), b256, 0, stream>>>(
            pbf, SDM, 64, DM,  qh, SDM, 64, DM,  B1, nullptr, HSS, SS, S,  wvb, 0, 64, S);
        gemmT<128,128,EPI_MASK,false,true,true,false><<<dim3(8, 8, 32), b256, 0, stream>>>(
            qh, SDM, 64, DM,  kh, SDM, 64, DM,  B2, nullptr, HSS, SS, S,  wvb, 0, 64, S);
        ptbuf = B1; sqkbuf = B2; ebuf = B3; pbuf = B1; s2buf = B2;
    }
    // E = exp(sQK @ P) + per-slice row sums, causal-K -> ebuf, psum
    gemmU<<<dim3(8, 8, 32), b256, 0, stream>>>(sqkbuf, ptbuf, ebuf, psum);
    // inv2[row] = 1 / (sum_slices psum * (t+1))  (2 MB read)
    sumfin<<<dim3(NB*H*S/256), b256, 0, stream>>>(psum, inv);
    if (!dual) {
        // pack[t][s] = elu(qh.ph)+1 -> B1 (packT dead)
        gemmT<128,128,EPI_PACK,false,false,true,false><<<dim3(8, 8, 32), b256, 0, stream>>>(
            qh, SDM, 64, DM,  pbf, SDM, 64, DM,  B1, nullptr, HSS, SS, S,  wvb, 0, 64, S);
    }
    // s2[t][s] = (E[t,:].P[s,:]) * inv2[t], causal-skip -> s2buf (sQK dead)
    gemmV<<<dim3(8, 8, 32), b256, 0, stream>>>(ebuf, pbuf, s2buf, inv);
    // attn_out[t][d] = s2 @ vh (B = vhT head-slice [d][s]), 64x64 tiles (512
    // blocks, 1 wave each), causal-K longest-first
    gemmT<64,64,EPI_BF,true,false,false,true><<<dim3(1, 16, 32), b64, 0, stream>>>(
        s2buf, HSS, SS, S,  vhT, (long)DM*S, (long)64*S, S,  ao, nullptr, SDM, 64, DM,
        wvb, 0, S, 64);
    // out = ao @ wc + b (f32), 64x128 tiles
    gemmT<64,128,EPI_OUT,false,false,false,false><<<dim3(8, 32, 1), b128, 0, stream>>>(
        ao, 0, 0, DM,  wcT, 0, 0, DM,  out, nullptr, 0, 0, DM,  wcb, 0, DM, DM);
}